// Round 8
// baseline (1180.211 us; speedup 1.0000x reference)
//
#include <hip/hip_runtime.h>
#include <hip/hip_bf16.h>
#include <cstdint>
#include <cstddef>

// Problem constants (match reference)
#define B_CL   8
#define NPTS   2048
#define S1CNT  1024
#define S2CNT  256
#define KNBR   64

typedef unsigned short ushort;
typedef __attribute__((ext_vector_type(8))) short short8b;  // 8 bf16 = MFMA A/B frag
typedef __attribute__((ext_vector_type(4))) float f32x4;    // MFMA C/D frag

__device__ __forceinline__ ushort f2bf(float f) {
    union { __hip_bfloat16 h; ushort u; } v;
    v.h = __float2bfloat16(f);
    return v.u;
}
__device__ __forceinline__ float bf2f(ushort u) {
    return __uint_as_float(((unsigned)u) << 16);
}
__device__ __forceinline__ short8b ldfrag(const ushort* p) {
    return *(const short8b*)p;
}
__device__ __forceinline__ f32x4 mfma16(short8b a, short8b b, f32x4 c) {
    return __builtin_amdgcn_mfma_f32_16x16x32_bf16(a, b, c, 0, 0, 0);
}

// Exact f32 squared distance in the reference's summation order.
__device__ __forceinline__ float dist2_exact(float ax, float ay, float az,
                                             float bx, float by, float bz) {
    float dx = __fsub_rn(ax, bx);
    float dy = __fsub_rn(ay, by);
    float dz = __fsub_rn(az, bz);
    return __fadd_rn(__fadd_rn(__fmul_rn(dx, dx), __fmul_rn(dy, dy)), __fmul_rn(dz, dz));
}

// 64-lane max-reduce of a u64 key via DPP. Result valid in lane 63.
__device__ __forceinline__ unsigned long long wave_max_u64(unsigned long long k) {
#define DPP_STEP(CTRL) {                                                            \
    unsigned lo = (unsigned)k, hi = (unsigned)(k >> 32);                            \
    unsigned nlo = (unsigned)__builtin_amdgcn_update_dpp((int)lo, (int)lo, CTRL,    \
                                                         0xf, 0xf, false);          \
    unsigned nhi = (unsigned)__builtin_amdgcn_update_dpp((int)hi, (int)hi, CTRL,    \
                                                         0xf, 0xf, false);          \
    unsigned long long nk = ((unsigned long long)nhi << 32) | nlo;                  \
    if (nk > k) k = nk;                                                             \
}
    DPP_STEP(0x111);  // row_shr:1
    DPP_STEP(0x112);  // row_shr:2
    DPP_STEP(0x114);  // row_shr:4
    DPP_STEP(0x118);  // row_shr:8
    DPP_STEP(0x142);  // row_bcast:15
    DPP_STEP(0x143);  // row_bcast:31
#undef DPP_STEP
    return k;
}

// ---------------------------------------------------------------------------
// Farthest point sampling, CPB clouds interleaved per block (one shared
// barrier per iteration; each cloud's dependent-latency chain hides under the
// other cloud's VALU issue). In-loop barrier is raw lgkmcnt-only (no vmem
// drain) so the per-iteration global cpos store never enters the sync path.
// Selection is bit-exact: d2 in reference op order; key=(d2,~idx) u64-max.
// ---------------------------------------------------------------------------
template <int N, int S, int CPB>
__device__ __forceinline__ void fps_body(const float* __restrict__ pos,
                                         float* __restrict__ cpos,
                                         int b0, char* smem) {
    constexpr int PPT = N / 256;
    float* px = (float*)smem;              // [CPB][N]
    float* py = px + CPB * N;
    float* pz = py + CPB * N;
    unsigned long long* kbuf = (unsigned long long*)(pz + CPB * N);  // [2][CPB][4]

    const int tid = threadIdx.x;

    float ox[CPB][PPT], oy[CPB][PPT], oz[CPB][PPT], d[CPB][PPT];
    #pragma unroll
    for (int c = 0; c < CPB; ++c) {
        const float* P = pos + (size_t)(b0 + c) * N * 3;
        #pragma unroll
        for (int j = 0; j < PPT; ++j) {
            int idx = tid + 256 * j;
            float x = P[idx * 3 + 0];
            float y = P[idx * 3 + 1];
            float z = P[idx * 3 + 2];
            px[c * N + idx] = x; py[c * N + idx] = y; pz[c * N + idx] = z;
            ox[c][j] = x; oy[c][j] = y; oz[c][j] = z;
            d[c][j] = 1e30f;
        }
    }
    __syncthreads();

    float cx[CPB], cy[CPB], cz[CPB];
    #pragma unroll
    for (int c = 0; c < CPB; ++c) {
        cx[c] = px[c * N]; cy[c] = py[c * N]; cz[c] = pz[c * N];
        if (tid == c * 64) {
            float* cp = cpos + (size_t)(b0 + c) * S * 3;
            cp[0] = cx[c]; cp[1] = cy[c]; cp[2] = cz[c];
        }
    }

    for (int i = 1; i < S; ++i) {
        unsigned long long key[CPB];
        #pragma unroll
        for (int c = 0; c < CPB; ++c) {
            float bv = -1.0f;
            int   bi = 0;
            #pragma unroll
            for (int j = 0; j < PPT; ++j) {
                int idx = tid + 256 * j;
                float dd = dist2_exact(ox[c][j], oy[c][j], oz[c][j], cx[c], cy[c], cz[c]);
                float nd = fminf(d[c][j], dd);
                d[c][j] = nd;
                if (nd > bv) { bv = nd; bi = idx; }
            }
            key[c] = ((unsigned long long)__float_as_uint(bv) << 32) | (unsigned)(~bi);
            key[c] = wave_max_u64(key[c]);
        }

        const int par = i & 1;
        if ((tid & 63) == 63) {
            #pragma unroll
            for (int c = 0; c < CPB; ++c)
                kbuf[(par * CPB + c) * 4 + (tid >> 6)] = key[c];
        }
        // raw barrier: wait LDS writes only; pending global cpos stores are
        // fire-and-forget (nobody reads cpos until kernel end -> endpgm drain)
        asm volatile("s_waitcnt lgkmcnt(0)" ::: "memory");
        __builtin_amdgcn_s_barrier();
        __builtin_amdgcn_sched_barrier(0);

        #pragma unroll
        for (int c = 0; c < CPB; ++c) {
            unsigned long long kk = kbuf[(par * CPB + c) * 4 + 0];
            unsigned long long k1 = kbuf[(par * CPB + c) * 4 + 1];
            unsigned long long k2 = kbuf[(par * CPB + c) * 4 + 2];
            unsigned long long k3 = kbuf[(par * CPB + c) * 4 + 3];
            if (k1 > kk) kk = k1;
            if (k2 > kk) kk = k2;
            if (k3 > kk) kk = k3;
            const int nxt = (int)(~(unsigned)kk);
            cx[c] = px[c * N + nxt];
            cy[c] = py[c * N + nxt];
            cz[c] = pz[c * N + nxt];
            if (tid == c * 64) {
                float* cp = cpos + ((size_t)(b0 + c) * S + i) * 3;
                cp[0] = cx[c]; cp[1] = cy[c]; cp[2] = cz[c];
            }
        }
    }
}

template <int N, int S, int CPB>
__global__ __launch_bounds__(256) void fps_kernel(const float* __restrict__ pos,
                                                  float* __restrict__ cpos) {
    __shared__ __align__(16) char smem[CPB * N * 3 * 4 + 2 * CPB * 4 * 8];
    fps_body<N, S, CPB>(pos, cpos, blockIdx.x * CPB, smem);
}

// ---------------------------------------------------------------------------
// Radius neighbor search body (bit-exact top_k semantics), smem passed in.
// ---------------------------------------------------------------------------
template <int N>
__device__ __forceinline__ void radius_body(const float* __restrict__ pos,
                                            const float* __restrict__ cpos,
                                            int M, float rr,
                                            int* __restrict__ nbr,
                                            int* __restrict__ cnt,
                                            char* smem, int bm) {
    unsigned long long* list = (unsigned long long*)smem;
    int* c_sh = (int*)(smem + (size_t)N * 8);

    const int b   = bm / M;
    const int tid = threadIdx.x;
    const float* P = pos + (size_t)b * N * 3;

    const float cx = cpos[bm * 3 + 0];
    const float cy = cpos[bm * 3 + 1];
    const float cz = cpos[bm * 3 + 2];

    if (tid == 0) *c_sh = 0;
    __syncthreads();

    for (int i = tid; i < N; i += 256) {
        float d2 = dist2_exact(cx, cy, cz, P[i * 3], P[i * 3 + 1], P[i * 3 + 2]);
        if (d2 <= rr) {
            int slot = atomicAdd(c_sh, 1);
            list[slot] = ((unsigned long long)__float_as_uint(d2) << 32) | (unsigned int)i;
        }
    }
    __syncthreads();
    int C = *c_sh;

    if (C <= KNBR) {
        if (tid < C) nbr[(size_t)bm * KNBR + tid] = (int)(list[tid] & 0xffffffffu);
        if (tid == 0) cnt[bm] = C;
        return;
    }

    int P2 = 1;
    while (P2 < C) P2 <<= 1;
    for (int i = C + tid; i < P2; i += 256) list[i] = ~0ULL;
    __syncthreads();
    for (int k = 2; k <= P2; k <<= 1) {
        for (int j = k >> 1; j > 0; j >>= 1) {
            for (int i = tid; i < P2; i += 256) {
                int l = i ^ j;
                if (l > i) {
                    unsigned long long a = list[i], bb = list[l];
                    bool up = ((i & k) == 0);
                    if ((a > bb) == up) { list[i] = bb; list[l] = a; }
                }
            }
            __syncthreads();
        }
    }
    if (tid < KNBR) nbr[(size_t)bm * KNBR + tid] = (int)(list[tid] & 0xffffffffu);
    if (tid == 0) cnt[bm] = KNBR;
}

template <int N>
__global__ __launch_bounds__(256) void radius_kernel(const float* __restrict__ pos,
                                                     const float* __restrict__ cpos,
                                                     int M, float rr,
                                                     int* __restrict__ nbr,
                                                     int* __restrict__ cnt) {
    __shared__ __align__(16) char smem[(size_t)N * 8 + 16];
    radius_body<N>(pos, cpos, M, rr, nbr, cnt, smem, blockIdx.x);
}

// ---------------------------------------------------------------------------
// Fused dispatch: blocks [0, 8192) = radius search stage 1; blocks [8192,
// 8192+4) = FPS stage 2 (needs only cpos1, independent of radius output; its
// ~100us wall hides inside this dispatch instead of serializing after it).
// ---------------------------------------------------------------------------
__global__ __launch_bounds__(256) void radius1_fps2_kernel(const float* __restrict__ pos,
                                                           const float* __restrict__ cpos1,
                                                           float rr1,
                                                           int* __restrict__ nbr1,
                                                           int* __restrict__ cnt1,
                                                           float* __restrict__ cpos2) {
    constexpr int    RB   = B_CL * S1CNT;                       // 8192 radius blocks
    constexpr size_t SM_R = (size_t)NPTS * 8 + 16;              // 16.4 KB
    constexpr size_t SM_F = (size_t)2 * S1CNT * 3 * 4 + 2 * 2 * 4 * 8;  // 24.7 KB
    __shared__ __align__(16) char smem[SM_R > SM_F ? SM_R : SM_F];
    if (blockIdx.x < RB)
        radius_body<NPTS>(pos, cpos1, S1CNT, rr1, nbr1, cnt1, smem, blockIdx.x);
    else
        fps_body<S1CNT, S2CNT, 2>(cpos1, cpos2, (int)(blockIdx.x - RB) * 2, smem);
}

// ---------------------------------------------------------------------------
// Weight prep: W [K][N] f32  ->  Wt [N][Kpad] bf16 (zero-padded rows k >= K).
// ---------------------------------------------------------------------------
__global__ __launch_bounds__(64) void wprep_kernel(const float* __restrict__ W,
                                                   ushort* __restrict__ Wt,
                                                   int K, int N, int Kpad) {
    const int n = blockIdx.x;
    for (int k = threadIdx.x; k < Kpad; k += 64)
        Wt[(size_t)n * Kpad + k] = (k < K) ? f2bf(W[(size_t)k * N + n]) : (ushort)0;
}

// ---------------------------------------------------------------------------
// SA1 PointNetConv via MFMA: [3 -> 64 -> 64 -> 128] per centroid, max-agg.
// ---------------------------------------------------------------------------
__global__ __launch_bounds__(256) void conv1_kernel(const float* __restrict__ pos,
                                                    const float* __restrict__ cpos,
                                                    const int* __restrict__ nbr,
                                                    const int* __restrict__ cnt,
                                                    const ushort* __restrict__ Wt1, const float* __restrict__ b1,
                                                    const ushort* __restrict__ Wt2, const float* __restrict__ b2,
                                                    const ushort* __restrict__ Wt3, const float* __restrict__ b3,
                                                    ushort* __restrict__ h1) {
    __shared__ ushort act1[64 * 72];
    __shared__ ushort act2[64 * 72];
    __shared__ int    snbr[KNBR];

    const int bm  = blockIdx.x;          // b*S1 + m
    const int b   = bm >> 10;            // S1CNT = 1024
    const int tid = threadIdx.x;
    const int C   = cnt[bm];

    const float cx = cpos[bm * 3 + 0];
    const float cy = cpos[bm * 3 + 1];
    const float cz = cpos[bm * 3 + 2];

    if (tid < KNBR) snbr[tid] = (tid < C) ? nbr[(size_t)bm * KNBR + tid] : 0;
    __syncthreads();

    const int lane = tid & 63, w = tid >> 6;
    const int lrow = lane & 15;          // frag row/col within 16
    const int lk8  = (lane >> 4) * 8;    // frag k-base
    const int rbase = (lane >> 4) * 4;   // C-frag row base
    const f32x4 zz = {0.f, 0.f, 0.f, 0.f};

    // ---- build A0 frags in registers (K=3, k>=3 zero; lanes with k-base>=8 zero)
    short8b a0[4];
    #pragma unroll
    for (int mt = 0; mt < 4; ++mt) {
        short8b a = {0, 0, 0, 0, 0, 0, 0, 0};
        if (lane < 16) {
            const int nb = snbr[mt * 16 + lrow];
            const float* pp = pos + ((size_t)b * NPTS + nb) * 3;
            a[0] = (short)f2bf(pp[0] - cx);
            a[1] = (short)f2bf(pp[1] - cy);
            a[2] = (short)f2bf(pp[2] - cz);
        }
        a0[mt] = a;
    }

    // ---- L1: K=3 (1 kstep), N=64 -> 1 ntile per wave
    {
        const int nt = w;
        short8b bf = ldfrag(Wt1 + (size_t)(nt * 16 + lrow) * 40 + lk8);
        const float bj = b1[nt * 16 + lrow];
        #pragma unroll
        for (int mt = 0; mt < 4; ++mt) {
            f32x4 acc = mfma16(a0[mt], bf, zz);
            #pragma unroll
            for (int r = 0; r < 4; ++r) {
                const int row = mt * 16 + rbase + r;
                act1[row * 72 + nt * 16 + lrow] = f2bf(fmaxf(acc[r] + bj, 0.f));
            }
        }
    }
    __syncthreads();

    // ---- L2: K=64 (2 ksteps), N=64 -> 1 ntile per wave
    {
        short8b af[4][2];
        #pragma unroll
        for (int mt = 0; mt < 4; ++mt)
            #pragma unroll
            for (int ks = 0; ks < 2; ++ks)
                af[mt][ks] = ldfrag(&act1[(mt * 16 + lrow) * 72 + ks * 32 + lk8]);
        const int nt = w;
        short8b bf0 = ldfrag(Wt2 + (size_t)(nt * 16 + lrow) * 72 + 0  + lk8);
        short8b bf1 = ldfrag(Wt2 + (size_t)(nt * 16 + lrow) * 72 + 32 + lk8);
        const float bj = b2[nt * 16 + lrow];
        #pragma unroll
        for (int mt = 0; mt < 4; ++mt) {
            f32x4 acc = mfma16(af[mt][0], bf0, zz);
            acc = mfma16(af[mt][1], bf1, acc);
            #pragma unroll
            for (int r = 0; r < 4; ++r) {
                const int row = mt * 16 + rbase + r;
                act2[row * 72 + nt * 16 + lrow] = f2bf(fmaxf(acc[r] + bj, 0.f));
            }
        }
    }
    __syncthreads();

    // ---- L3: K=64 (2 ksteps), N=128 -> 2 ntiles per wave; no relu; masked max
    {
        short8b af[4][2];
        #pragma unroll
        for (int mt = 0; mt < 4; ++mt)
            #pragma unroll
            for (int ks = 0; ks < 2; ++ks)
                af[mt][ks] = ldfrag(&act2[(mt * 16 + lrow) * 72 + ks * 32 + lk8]);
        #pragma unroll
        for (int nti = 0; nti < 2; ++nti) {
            const int nt = w * 2 + nti;
            short8b bf0 = ldfrag(Wt3 + (size_t)(nt * 16 + lrow) * 72 + 0  + lk8);
            short8b bf1 = ldfrag(Wt3 + (size_t)(nt * 16 + lrow) * 72 + 32 + lk8);
            const float bj = b3[nt * 16 + lrow];
            float vm = -3.4e38f;
            #pragma unroll
            for (int mt = 0; mt < 4; ++mt) {
                f32x4 acc = mfma16(af[mt][0], bf0, zz);
                acc = mfma16(af[mt][1], bf1, acc);
                #pragma unroll
                for (int r = 0; r < 4; ++r) {
                    const int m = mt * 16 + rbase + r;
                    if (m < C) vm = fmaxf(vm, acc[r] + bj);
                }
            }
            vm = fmaxf(vm, __shfl_xor(vm, 16));
            vm = fmaxf(vm, __shfl_xor(vm, 32));
            if (lane < 16) h1[(size_t)bm * 128 + nt * 16 + lrow] = f2bf(vm);
        }
    }
}

// ---------------------------------------------------------------------------
// SA2 PointNetConv via MFMA: [131 -> 128 -> 128 -> 256] per centroid, max-agg.
// ---------------------------------------------------------------------------
__global__ __launch_bounds__(256) void conv2_kernel(const ushort* __restrict__ x,     // h1 bf16 [B,S1,128]
                                                    const float* __restrict__ ppos,   // cpos1
                                                    const float* __restrict__ cpos,   // cpos2
                                                    const int* __restrict__ nbr,
                                                    const int* __restrict__ cnt,
                                                    const ushort* __restrict__ Wt1, const float* __restrict__ b1,
                                                    const ushort* __restrict__ Wt2, const float* __restrict__ b2,
                                                    const ushort* __restrict__ Wt3, const float* __restrict__ b3,
                                                    ushort* __restrict__ h2) {
    __shared__ ushort act0[64 * 168];    // also reused as act2 [64][136]
    __shared__ ushort act1[64 * 136];
    __shared__ int    snbr[KNBR];
    ushort* act2 = act0;

    const int bm  = blockIdx.x;          // b*S2 + m
    const int b   = bm >> 8;             // S2CNT = 256
    const int tid = threadIdx.x;
    const int C   = cnt[bm];

    const float cx = cpos[bm * 3 + 0];
    const float cy = cpos[bm * 3 + 1];
    const float cz = cpos[bm * 3 + 2];

    if (tid < KNBR) snbr[tid] = (tid < C) ? nbr[(size_t)bm * KNBR + tid] : 0;
    __syncthreads();

    // ---- stage act0: rows k=0..63 (neighbors), cols 0..127 = x feats, 128..130 rel, ..159 zero
    for (int e = tid; e < 1024; e += 256) {          // 64 rows x 16 chunks of 8 bf16
        const int k = e >> 4, c = (e & 15) * 8;
        short8b v = {0, 0, 0, 0, 0, 0, 0, 0};
        if (k < C) v = ldfrag(x + ((size_t)b * S1CNT + snbr[k]) * 128 + c);
        *(short8b*)&act0[k * 168 + c] = v;
    }
    if (tid < KNBR) {
        const int k = tid;
        float r0 = 0.f, r1 = 0.f, r2 = 0.f;
        if (k < C) {
            const float* pp = ppos + ((size_t)b * S1CNT + snbr[k]) * 3;
            r0 = pp[0] - cx; r1 = pp[1] - cy; r2 = pp[2] - cz;
        }
        act0[k * 168 + 128] = f2bf(r0);
        act0[k * 168 + 129] = f2bf(r1);
        act0[k * 168 + 130] = f2bf(r2);
        for (int c = 131; c < 160; ++c) act0[k * 168 + c] = 0;
    }
    __syncthreads();

    const int lane = tid & 63, w = tid >> 6;
    const int lrow = lane & 15;
    const int lk8  = (lane >> 4) * 8;
    const int rbase = (lane >> 4) * 4;
    const f32x4 zz = {0.f, 0.f, 0.f, 0.f};

    // ---- L1: K=131 (5 ksteps), N=128 -> 2 ntiles per wave
    {
        short8b af[4][5];
        #pragma unroll
        for (int mt = 0; mt < 4; ++mt)
            #pragma unroll
            for (int ks = 0; ks < 5; ++ks)
                af[mt][ks] = ldfrag(&act0[(mt * 16 + lrow) * 168 + ks * 32 + lk8]);
        #pragma unroll
        for (int nti = 0; nti < 2; ++nti) {
            const int nt = w * 2 + nti;
            f32x4 acc[4] = {zz, zz, zz, zz};
            #pragma unroll
            for (int ks = 0; ks < 5; ++ks) {
                short8b bf = ldfrag(Wt1 + (size_t)(nt * 16 + lrow) * 168 + ks * 32 + lk8);
                #pragma unroll
                for (int mt = 0; mt < 4; ++mt) acc[mt] = mfma16(af[mt][ks], bf, acc[mt]);
            }
            const float bj = b1[nt * 16 + lrow];
            #pragma unroll
            for (int mt = 0; mt < 4; ++mt)
                #pragma unroll
                for (int r = 0; r < 4; ++r) {
                    const int row = mt * 16 + rbase + r;
                    act1[row * 136 + nt * 16 + lrow] = f2bf(fmaxf(acc[mt][r] + bj, 0.f));
                }
        }
    }
    __syncthreads();

    // ---- L2: K=128 (4 ksteps), N=128 -> 2 ntiles per wave (act1 -> act2)
    {
        short8b af[4][4];
        #pragma unroll
        for (int mt = 0; mt < 4; ++mt)
            #pragma unroll
            for (int ks = 0; ks < 4; ++ks)
                af[mt][ks] = ldfrag(&act1[(mt * 16 + lrow) * 136 + ks * 32 + lk8]);
        #pragma unroll
        for (int nti = 0; nti < 2; ++nti) {
            const int nt = w * 2 + nti;
            f32x4 acc[4] = {zz, zz, zz, zz};
            #pragma unroll
            for (int ks = 0; ks < 4; ++ks) {
                short8b bf = ldfrag(Wt2 + (size_t)(nt * 16 + lrow) * 136 + ks * 32 + lk8);
                #pragma unroll
                for (int mt = 0; mt < 4; ++mt) acc[mt] = mfma16(af[mt][ks], bf, acc[mt]);
            }
            const float bj = b2[nt * 16 + lrow];
            #pragma unroll
            for (int mt = 0; mt < 4; ++mt)
                #pragma unroll
                for (int r = 0; r < 4; ++r) {
                    const int row = mt * 16 + rbase + r;
                    act2[row * 136 + nt * 16 + lrow] = f2bf(fmaxf(acc[mt][r] + bj, 0.f));
                }
        }
    }
    __syncthreads();

    // ---- L3: K=128 (4 ksteps), N=256 -> 4 ntiles per wave; no relu; masked max
    {
        short8b af[4][4];
        #pragma unroll
        for (int mt = 0; mt < 4; ++mt)
            #pragma unroll
            for (int ks = 0; ks < 4; ++ks)
                af[mt][ks] = ldfrag(&act2[(mt * 16 + lrow) * 136 + ks * 32 + lk8]);
        #pragma unroll
        for (int nti = 0; nti < 4; ++nti) {
            const int nt = w * 4 + nti;
            f32x4 acc[4] = {zz, zz, zz, zz};
            #pragma unroll
            for (int ks = 0; ks < 4; ++ks) {
                short8b bf = ldfrag(Wt3 + (size_t)(nt * 16 + lrow) * 136 + ks * 32 + lk8);
                #pragma unroll
                for (int mt = 0; mt < 4; ++mt) acc[mt] = mfma16(af[mt][ks], bf, acc[mt]);
            }
            const float bj = b3[nt * 16 + lrow];
            float vm = -3.4e38f;
            #pragma unroll
            for (int mt = 0; mt < 4; ++mt)
                #pragma unroll
                for (int r = 0; r < 4; ++r) {
                    const int m = mt * 16 + rbase + r;
                    if (m < C) vm = fmaxf(vm, acc[mt][r] + bj);
                }
            vm = fmaxf(vm, __shfl_xor(vm, 16));
            vm = fmaxf(vm, __shfl_xor(vm, 32));
            if (lane < 16) h2[(size_t)bm * 256 + nt * 16 + lrow] = f2bf(vm);
        }
    }
}

// ---------------------------------------------------------------------------
// Global MLP [259 -> 256 -> 512 -> 1024]: 4 rows per block, VALU fp32,
// atomic-max into order-preserving-encoded uint buffer. h2 input is bf16.
// ---------------------------------------------------------------------------
__device__ __forceinline__ unsigned enc_f32(float f) {
    unsigned u = __float_as_uint(f);
    return (u & 0x80000000u) ? ~u : (u | 0x80000000u);
}

__global__ __launch_bounds__(256) void gmax_init_kernel(unsigned* __restrict__ gmax) {
    gmax[blockIdx.x * 256 + threadIdx.x] = 0u;   // encodes below any finite float
}

__global__ __launch_bounds__(256) void mlp3_kernel(const ushort* __restrict__ h2,
                                                   const float* __restrict__ cpos2,
                                                   const float* __restrict__ W1, const float* __restrict__ b1,
                                                   const float* __restrict__ W2, const float* __restrict__ b2,
                                                   const float* __restrict__ W3, const float* __restrict__ b3,
                                                   unsigned* __restrict__ gmax) {
    __shared__ float in4[4][260];
    __shared__ float a1s[4][256];
    __shared__ float a2s[4][512];

    const int bm0 = blockIdx.x * 4;      // first of 4 consecutive s-rows (same cloud)
    const int bcl = bm0 >> 8;            // S2CNT = 256
    const int tid = threadIdx.x;

    #pragma unroll
    for (int r = 0; r < 4; ++r) {
        in4[r][tid] = bf2f(h2[(size_t)(bm0 + r) * 256 + tid]);
        if (tid < 3) in4[r][256 + tid] = cpos2[(bm0 + r) * 3 + tid];
    }
    __syncthreads();

    {   // L1: K=259, N=256
        const float bj = b1[tid];
        float acc[4] = {bj, bj, bj, bj};
        for (int i = 0; i < 259; ++i) {
            const float w = W1[i * 256 + tid];
            #pragma unroll
            for (int r = 0; r < 4; ++r) acc[r] += in4[r][i] * w;
        }
        #pragma unroll
        for (int r = 0; r < 4; ++r) a1s[r][tid] = fmaxf(acc[r], 0.f);
    }
    __syncthreads();

    {   // L2: K=256, N=512
        const float bj0 = b2[tid], bj1 = b2[tid + 256];
        float acc0[4] = {bj0, bj0, bj0, bj0};
        float acc1[4] = {bj1, bj1, bj1, bj1};
        for (int i = 0; i < 256; ++i) {
            const float w0 = W2[i * 512 + tid];
            const float w1 = W2[i * 512 + tid + 256];
            #pragma unroll
            for (int r = 0; r < 4; ++r) {
                const float a = a1s[r][i];
                acc0[r] += a * w0;
                acc1[r] += a * w1;
            }
        }
        #pragma unroll
        for (int r = 0; r < 4; ++r) {
            a2s[r][tid]       = fmaxf(acc0[r], 0.f);
            a2s[r][tid + 256] = fmaxf(acc1[r], 0.f);
        }
    }
    __syncthreads();

    {   // L3: K=512, N=1024
        float acc[4][4];
        #pragma unroll
        for (int q = 0; q < 4; ++q) {
            const float bj = b3[tid + 256 * q];
            #pragma unroll
            for (int r = 0; r < 4; ++r) acc[q][r] = bj;
        }
        for (int i = 0; i < 512; ++i) {
            float av[4];
            #pragma unroll
            for (int r = 0; r < 4; ++r) av[r] = a2s[r][i];
            #pragma unroll
            for (int q = 0; q < 4; ++q) {
                const float w = W3[i * 1024 + 256 * q + tid];
                #pragma unroll
                for (int r = 0; r < 4; ++r) acc[q][r] += av[r] * w;
            }
        }
        #pragma unroll
        for (int q = 0; q < 4; ++q)
            #pragma unroll
            for (int r = 0; r < 4; ++r)
                atomicMax(&gmax[(size_t)bcl * 1024 + 256 * q + tid], enc_f32(acc[q][r]));
    }
}

__global__ __launch_bounds__(256) void gmax_decode_kernel(const unsigned* __restrict__ gmax,
                                                          float* __restrict__ out) {
    int t = blockIdx.x * 256 + threadIdx.x;
    unsigned u = gmax[t];
    out[t] = (u & 0x80000000u) ? __uint_as_float(u ^ 0x80000000u) : __uint_as_float(~u);
}

// ---------------------------------------------------------------------------
extern "C" void kernel_launch(void* const* d_in, const int* in_sizes, int n_in,
                              void* d_out, int out_size, void* d_ws, size_t ws_size,
                              hipStream_t stream) {
    (void)in_sizes; (void)n_in; (void)out_size; (void)ws_size;

    const float* pos = (const float*)d_in[0];
    const float* W1a = (const float*)d_in[1];  const float* b1a = (const float*)d_in[2];
    const float* W1b = (const float*)d_in[3];  const float* b1b = (const float*)d_in[4];
    const float* W1c = (const float*)d_in[5];  const float* b1c = (const float*)d_in[6];
    const float* W2a = (const float*)d_in[7];  const float* b2a = (const float*)d_in[8];
    const float* W2b = (const float*)d_in[9];  const float* b2b = (const float*)d_in[10];
    const float* W2c = (const float*)d_in[11]; const float* b2c = (const float*)d_in[12];
    const float* W3a = (const float*)d_in[13]; const float* b3a = (const float*)d_in[14];
    const float* W3b = (const float*)d_in[15]; const float* b3b = (const float*)d_in[16];
    const float* W3c = (const float*)d_in[17]; const float* b3c = (const float*)d_in[18];

    float* out = (float*)d_out;

    char* ws = (char*)d_ws;
    auto alloc = [&](size_t bytes) {
        char* p = ws;
        ws += (bytes + 255) & ~(size_t)255;
        return p;
    };
    float*    cpos1 = (float*)   alloc((size_t)B_CL * S1CNT * 3 * 4);
    int*      nbr1  = (int*)     alloc((size_t)B_CL * S1CNT * KNBR * 4);
    int*      cnt1  = (int*)     alloc((size_t)B_CL * S1CNT * 4);
    ushort*   h1    = (ushort*)  alloc((size_t)B_CL * S1CNT * 128 * 2);
    float*    cpos2 = (float*)   alloc((size_t)B_CL * S2CNT * 3 * 4);
    int*      nbr2  = (int*)     alloc((size_t)B_CL * S2CNT * KNBR * 4);
    int*      cnt2  = (int*)     alloc((size_t)B_CL * S2CNT * 4);
    ushort*   h2    = (ushort*)  alloc((size_t)B_CL * S2CNT * 256 * 2);
    unsigned* gmax  = (unsigned*)alloc((size_t)B_CL * 1024 * 4);
    ushort*   Wt1a  = (ushort*)  alloc((size_t)64  * 40  * 2);
    ushort*   Wt1b  = (ushort*)  alloc((size_t)64  * 72  * 2);
    ushort*   Wt1c  = (ushort*)  alloc((size_t)128 * 72  * 2);
    ushort*   Wt2a  = (ushort*)  alloc((size_t)128 * 168 * 2);
    ushort*   Wt2b  = (ushort*)  alloc((size_t)128 * 136 * 2);
    ushort*   Wt2c  = (ushort*)  alloc((size_t)256 * 136 * 2);

    const float RR1 = (float)(0.2 * 0.2);
    const float RR2 = (float)(0.4 * 0.4);

    // weight prep (bf16 transpose, zero-padded)
    wprep_kernel<<<64,  64, 0, stream>>>(W1a, Wt1a, 3,   64,  40);
    wprep_kernel<<<64,  64, 0, stream>>>(W1b, Wt1b, 64,  64,  72);
    wprep_kernel<<<128, 64, 0, stream>>>(W1c, Wt1c, 64,  128, 72);
    wprep_kernel<<<128, 64, 0, stream>>>(W2a, Wt2a, 131, 128, 168);
    wprep_kernel<<<128, 64, 0, stream>>>(W2b, Wt2b, 128, 128, 136);
    wprep_kernel<<<256, 64, 0, stream>>>(W2c, Wt2c, 128, 256, 136);

    // SA module 1 (fps: 2 clouds interleaved per block -> 4 blocks)
    fps_kernel<NPTS, S1CNT, 2><<<B_CL / 2, 256, 0, stream>>>(pos, cpos1);
    // radius stage 1 fused with fps stage 2 (fps2 only needs cpos1)
    radius1_fps2_kernel<<<B_CL * S1CNT + B_CL / 2, 256, 0, stream>>>(pos, cpos1, RR1,
                                                                     nbr1, cnt1, cpos2);
    conv1_kernel<<<B_CL * S1CNT, 256, 0, stream>>>(pos, cpos1, nbr1, cnt1,
                                                   Wt1a, b1a, Wt1b, b1b, Wt1c, b1c, h1);
    // SA module 2
    radius_kernel<S1CNT><<<B_CL * S2CNT, 256, 0, stream>>>(cpos1, cpos2, S2CNT, RR2, nbr2, cnt2);
    conv2_kernel<<<B_CL * S2CNT, 256, 0, stream>>>(h1, cpos1, cpos2, nbr2, cnt2,
                                                   Wt2a, b2a, Wt2b, b2b, Wt2c, b2c, h2);
    // Global MLP + max pool
    gmax_init_kernel<<<(B_CL * 1024) / 256, 256, 0, stream>>>(gmax);
    mlp3_kernel<<<(B_CL * S2CNT) / 4, 256, 0, stream>>>(h2, cpos2,
                                                        W3a, b3a, W3b, b3b, W3c, b3c, gmax);
    gmax_decode_kernel<<<(B_CL * 1024) / 256, 256, 0, stream>>>(gmax, out);
}

// Round 10
// 986.806 us; speedup vs baseline: 1.1960x; 1.1960x over previous
//
#include <hip/hip_runtime.h>
#include <hip/hip_bf16.h>
#include <cstdint>
#include <cstddef>

// Problem constants (match reference)
#define B_CL   8
#define NPTS   2048
#define S1CNT  1024
#define S2CNT  256
#define KNBR   64

typedef unsigned short ushort;
typedef __attribute__((ext_vector_type(8))) short short8b;  // 8 bf16 = MFMA A/B frag
typedef __attribute__((ext_vector_type(4))) float f32x4;    // MFMA C/D frag

__device__ __forceinline__ ushort f2bf(float f) {
    union { __hip_bfloat16 h; ushort u; } v;
    v.h = __float2bfloat16(f);
    return v.u;
}
__device__ __forceinline__ float bf2f(ushort u) {
    return __uint_as_float(((unsigned)u) << 16);
}
__device__ __forceinline__ short8b ldfrag(const ushort* p) {
    return *(const short8b*)p;
}
__device__ __forceinline__ f32x4 mfma16(short8b a, short8b b, f32x4 c) {
    return __builtin_amdgcn_mfma_f32_16x16x32_bf16(a, b, c, 0, 0, 0);
}

// Exact f32 squared distance in the reference's summation order.
__device__ __forceinline__ float dist2_exact(float ax, float ay, float az,
                                             float bx, float by, float bz) {
    float dx = __fsub_rn(ax, bx);
    float dy = __fsub_rn(ay, by);
    float dz = __fsub_rn(az, bz);
    return __fadd_rn(__fadd_rn(__fmul_rn(dx, dx), __fmul_rn(dy, dy)), __fmul_rn(dz, dz));
}

// ---------------------------------------------------------------------------
// Farthest point sampling v2 (fixed). One cloud per block, NT threads.
// Per iteration:
//   update d + local argmax (PPT pts/thread)
//   wave reduce: v_max_f32 DPP chain -> readlane(63); min-index DPP chain for
//     exact first-max tie-break -> readlane(63)
//   the unique per-wave winner lane writes (key u64) + its coords (float4) to
//     its wave's LDS slot ONLY (no global store here — round-9 bug was all W
//     waves racing their wave-local winner into cpos[b*S+i])
//   raw lgkmcnt-barrier (no vmem drain), all threads resolve the W wave
//     winners in ONE LDS round trip, THEN tid==0 alone streams the resolved
//     block winner to cpos (fire-and-forget vmem, outside the sync path).
// ---------------------------------------------------------------------------
template <int N, int S, int NT>
__device__ __forceinline__ void fps_body2(const float* __restrict__ pos,
                                          float* __restrict__ cpos,
                                          int b, char* smem) {
    constexpr int PPT = N / NT;
    constexpr int W   = NT / 64;
    unsigned long long* kbuf = (unsigned long long*)smem;               // [2][W]
    float4* cbuf = (float4*)(smem + 2 * W * sizeof(unsigned long long)); // [2][W]

    const int tid = threadIdx.x;
    const int wid = tid >> 6;
    const float* P = pos + (size_t)b * N * 3;

    float ox[PPT], oy[PPT], oz[PPT], d[PPT];
    #pragma unroll
    for (int j = 0; j < PPT; ++j) {
        const int idx = tid + NT * j;
        ox[j] = P[idx * 3 + 0];
        oy[j] = P[idx * 3 + 1];
        oz[j] = P[idx * 3 + 2];
        d[j]  = 1e30f;
    }
    float cx = P[0], cy = P[1], cz = P[2];
    if (tid == 0) {
        float* cp = cpos + (size_t)b * S * 3;
        cp[0] = cx; cp[1] = cy; cp[2] = cz;
    }

    for (int i = 1; i < S; ++i) {
        float bv = -1.0f;
        int   bi = 0;
        #pragma unroll
        for (int j = 0; j < PPT; ++j) {
            const int idx = tid + NT * j;
            const float dd = dist2_exact(ox[j], oy[j], oz[j], cx, cy, cz);
            const float nd = fminf(d[j], dd);
            d[j] = nd;
            if (nd > bv) { bv = nd; bi = idx; }
        }
        // wave max of bv -> lane 63 -> sgpr broadcast
        float m = bv;
#define FMAXD(CTRL) { int t_ = __builtin_amdgcn_update_dpp(__float_as_int(m), __float_as_int(m), CTRL, 0xf, 0xf, false); m = fmaxf(m, __int_as_float(t_)); }
        FMAXD(0x111) FMAXD(0x112) FMAXD(0x114) FMAXD(0x118) FMAXD(0x142) FMAXD(0x143)
#undef FMAXD
        const float wmax = __int_as_float(__builtin_amdgcn_readlane(__float_as_int(m), 63));
        // min point-index among lanes holding wmax (exact first-max tie-break)
        int ic = (bv == wmax) ? bi : 0x7fffffff;
#define IMIND(CTRL) { int t_ = __builtin_amdgcn_update_dpp(ic, ic, CTRL, 0xf, 0xf, false); ic = min(ic, t_); }
        IMIND(0x111) IMIND(0x112) IMIND(0x114) IMIND(0x118) IMIND(0x142) IMIND(0x143)
#undef IMIND
        const int wbi = __builtin_amdgcn_readlane(ic, 63);

        const int par = i & 1;
        if (bv == wmax && bi == wbi) {
            // unique winner lane of this wave: bi sets are disjoint per lane
            const int jw = bi / NT;   // = local j (tid < NT)
            float wx = ox[0], wy = oy[0], wz = oz[0];
            #pragma unroll
            for (int j = 1; j < PPT; ++j)
                if (jw == j) { wx = ox[j]; wy = oy[j]; wz = oz[j]; }
            kbuf[par * W + wid] = ((unsigned long long)__float_as_uint(bv) << 32) | (unsigned)(~bi);
            cbuf[par * W + wid] = make_float4(wx, wy, wz, 0.f);
        }
        // raw barrier: LDS-only wait; global stores never enter the sync path
        asm volatile("s_waitcnt lgkmcnt(0)" ::: "memory");
        __builtin_amdgcn_s_barrier();
        __builtin_amdgcn_sched_barrier(0);

        // resolve W wave-winners (keys + coords in one round trip, broadcast reads)
        unsigned long long kk = kbuf[par * W + 0];
        float4 cc = cbuf[par * W + 0];
        #pragma unroll
        for (int w2 = 1; w2 < W; ++w2) {
            const unsigned long long kw = kbuf[par * W + w2];
            const float4 cw = cbuf[par * W + w2];
            if (kw > kk) { kk = kw; cc = cw; }
        }
        cx = cc.x; cy = cc.y; cz = cc.z;
        // single designated writer exports the BLOCK winner (fix for round 9)
        if (tid == 0) {
            float* cp = cpos + ((size_t)b * S + i) * 3;
            cp[0] = cx; cp[1] = cy; cp[2] = cz;   // fire-and-forget (vmem)
        }
    }
}

// ---------------------------------------------------------------------------
// Radius neighbor search body (bit-exact top_k semantics), smem passed in.
// 256 threads.
// ---------------------------------------------------------------------------
template <int N>
__device__ __forceinline__ void radius_body(const float* __restrict__ pos,
                                            const float* __restrict__ cpos,
                                            int M, float rr,
                                            int* __restrict__ nbr,
                                            int* __restrict__ cnt,
                                            char* smem, int bm) {
    unsigned long long* list = (unsigned long long*)smem;
    int* c_sh = (int*)(smem + (size_t)N * 8);

    const int b   = bm / M;
    const int tid = threadIdx.x;
    const float* P = pos + (size_t)b * N * 3;

    const float cx = cpos[bm * 3 + 0];
    const float cy = cpos[bm * 3 + 1];
    const float cz = cpos[bm * 3 + 2];

    if (tid == 0) *c_sh = 0;
    __syncthreads();

    for (int i = tid; i < N; i += 256) {
        float d2 = dist2_exact(cx, cy, cz, P[i * 3], P[i * 3 + 1], P[i * 3 + 2]);
        if (d2 <= rr) {
            int slot = atomicAdd(c_sh, 1);
            list[slot] = ((unsigned long long)__float_as_uint(d2) << 32) | (unsigned int)i;
        }
    }
    __syncthreads();
    int C = *c_sh;

    if (C <= KNBR) {
        if (tid < C) nbr[(size_t)bm * KNBR + tid] = (int)(list[tid] & 0xffffffffu);
        if (tid == 0) cnt[bm] = C;
        return;
    }

    int P2 = 1;
    while (P2 < C) P2 <<= 1;
    for (int i = C + tid; i < P2; i += 256) list[i] = ~0ULL;
    __syncthreads();
    for (int k = 2; k <= P2; k <<= 1) {
        for (int j = k >> 1; j > 0; j >>= 1) {
            for (int i = tid; i < P2; i += 256) {
                int l = i ^ j;
                if (l > i) {
                    unsigned long long a = list[i], bb = list[l];
                    bool up = ((i & k) == 0);
                    if ((a > bb) == up) { list[i] = bb; list[l] = a; }
                }
            }
            __syncthreads();
        }
    }
    if (tid < KNBR) nbr[(size_t)bm * KNBR + tid] = (int)(list[tid] & 0xffffffffu);
    if (tid == 0) cnt[bm] = KNBR;
}

// ---------------------------------------------------------------------------
// Weight prep body: W [K][N] f32 -> Wt [N][Kpad] bf16, grid-stride 512 thr.
// ---------------------------------------------------------------------------
__device__ __forceinline__ void wprep_body(const float* __restrict__ W,
                                           ushort* __restrict__ Wt,
                                           int K, int N, int Kpad) {
    const int total = N * Kpad;
    for (int e = threadIdx.x; e < total; e += 512) {
        const int n = e / Kpad, k = e - n * Kpad;
        Wt[e] = (k < K) ? f2bf(W[(size_t)k * N + n]) : (ushort)0;
    }
}

// ---------------------------------------------------------------------------
// Fused dispatch 1: blocks [0,8) = FPS stage 1 (512 thr); blocks [8,14) =
// bf16 weight transposes (fill idle CUs during the serial FPS).
// ---------------------------------------------------------------------------
__global__ __launch_bounds__(512) void fps1_wprep_kernel(
    const float* __restrict__ pos, float* __restrict__ cpos1,
    const float* __restrict__ W1a, ushort* __restrict__ Wt1a,
    const float* __restrict__ W1b, ushort* __restrict__ Wt1b,
    const float* __restrict__ W1c, ushort* __restrict__ Wt1c,
    const float* __restrict__ W2a, ushort* __restrict__ Wt2a,
    const float* __restrict__ W2b, ushort* __restrict__ Wt2b,
    const float* __restrict__ W2c, ushort* __restrict__ Wt2c) {
    __shared__ __align__(16) char smem[2 * 8 * 8 + 2 * 8 * 16];
    const int bx = blockIdx.x;
    if (bx < B_CL) { fps_body2<NPTS, S1CNT, 512>(pos, cpos1, bx, smem); return; }
    switch (bx - B_CL) {
        case 0: wprep_body(W1a, Wt1a, 3,   64,  40);  break;
        case 1: wprep_body(W1b, Wt1b, 64,  64,  72);  break;
        case 2: wprep_body(W1c, Wt1c, 64,  128, 72);  break;
        case 3: wprep_body(W2a, Wt2a, 131, 128, 168); break;
        case 4: wprep_body(W2b, Wt2b, 128, 128, 136); break;
        case 5: wprep_body(W2c, Wt2c, 128, 256, 136); break;
        default: break;
    }
}

// ---------------------------------------------------------------------------
// Fused dispatch 2: blocks [0, 8192) = radius stage 1; blocks [8192, 8200) =
// FPS stage 2 (needs only cpos1; hides inside this dispatch).
// ---------------------------------------------------------------------------
__global__ __launch_bounds__(256) void radius1_fps2_kernel(const float* __restrict__ pos,
                                                           const float* __restrict__ cpos1,
                                                           float rr1,
                                                           int* __restrict__ nbr1,
                                                           int* __restrict__ cnt1,
                                                           float* __restrict__ cpos2) {
    constexpr int    RB   = B_CL * S1CNT;                 // 8192 radius blocks
    constexpr size_t SM_R = (size_t)NPTS * 8 + 16;        // 16.4 KB
    __shared__ __align__(16) char smem[SM_R];
    if (blockIdx.x < RB)
        radius_body<NPTS>(pos, cpos1, S1CNT, rr1, nbr1, cnt1, smem, blockIdx.x);
    else
        fps_body2<S1CNT, S2CNT, 256>(cpos1, cpos2, (int)(blockIdx.x - RB), smem);
}

// ---------------------------------------------------------------------------
// SA1 PointNetConv via MFMA: [3 -> 64 -> 64 -> 128] per centroid, max-agg.
// ---------------------------------------------------------------------------
__device__ __forceinline__ void conv1_body(const float* __restrict__ pos,
                                           const float* __restrict__ cpos,
                                           const int* __restrict__ nbr,
                                           const int* __restrict__ cnt,
                                           const ushort* __restrict__ Wt1, const float* __restrict__ b1,
                                           const ushort* __restrict__ Wt2, const float* __restrict__ b2,
                                           const ushort* __restrict__ Wt3, const float* __restrict__ b3,
                                           ushort* __restrict__ h1,
                                           int bm, char* smem) {
    ushort* act1 = (ushort*)smem;            // [64*72]
    ushort* act2 = act1 + 64 * 72;           // [64*72]
    int*    snbr = (int*)(act2 + 64 * 72);   // [KNBR]

    const int b   = bm >> 10;            // S1CNT = 1024
    const int tid = threadIdx.x;
    const int C   = cnt[bm];

    const float cx = cpos[bm * 3 + 0];
    const float cy = cpos[bm * 3 + 1];
    const float cz = cpos[bm * 3 + 2];

    if (tid < KNBR) snbr[tid] = (tid < C) ? nbr[(size_t)bm * KNBR + tid] : 0;
    __syncthreads();

    const int lane = tid & 63, w = tid >> 6;
    const int lrow = lane & 15;          // frag row/col within 16
    const int lk8  = (lane >> 4) * 8;    // frag k-base
    const int rbase = (lane >> 4) * 4;   // C-frag row base
    const f32x4 zz = {0.f, 0.f, 0.f, 0.f};

    // ---- build A0 frags in registers (K=3, k>=3 zero; lanes with k-base>=8 zero)
    short8b a0[4];
    #pragma unroll
    for (int mt = 0; mt < 4; ++mt) {
        short8b a = {0, 0, 0, 0, 0, 0, 0, 0};
        if (lane < 16) {
            const int nb = snbr[mt * 16 + lrow];
            const float* pp = pos + ((size_t)b * NPTS + nb) * 3;
            a[0] = (short)f2bf(pp[0] - cx);
            a[1] = (short)f2bf(pp[1] - cy);
            a[2] = (short)f2bf(pp[2] - cz);
        }
        a0[mt] = a;
    }

    // ---- L1: K=3 (1 kstep), N=64 -> 1 ntile per wave
    {
        const int nt = w;
        short8b bf = ldfrag(Wt1 + (size_t)(nt * 16 + lrow) * 40 + lk8);
        const float bj = b1[nt * 16 + lrow];
        #pragma unroll
        for (int mt = 0; mt < 4; ++mt) {
            f32x4 acc = mfma16(a0[mt], bf, zz);
            #pragma unroll
            for (int r = 0; r < 4; ++r) {
                const int row = mt * 16 + rbase + r;
                act1[row * 72 + nt * 16 + lrow] = f2bf(fmaxf(acc[r] + bj, 0.f));
            }
        }
    }
    __syncthreads();

    // ---- L2: K=64 (2 ksteps), N=64 -> 1 ntile per wave
    {
        short8b af[4][2];
        #pragma unroll
        for (int mt = 0; mt < 4; ++mt)
            #pragma unroll
            for (int ks = 0; ks < 2; ++ks)
                af[mt][ks] = ldfrag(&act1[(mt * 16 + lrow) * 72 + ks * 32 + lk8]);
        const int nt = w;
        short8b bf0 = ldfrag(Wt2 + (size_t)(nt * 16 + lrow) * 72 + 0  + lk8);
        short8b bf1 = ldfrag(Wt2 + (size_t)(nt * 16 + lrow) * 72 + 32 + lk8);
        const float bj = b2[nt * 16 + lrow];
        #pragma unroll
        for (int mt = 0; mt < 4; ++mt) {
            f32x4 acc = mfma16(af[mt][0], bf0, zz);
            acc = mfma16(af[mt][1], bf1, acc);
            #pragma unroll
            for (int r = 0; r < 4; ++r) {
                const int row = mt * 16 + rbase + r;
                act2[row * 72 + nt * 16 + lrow] = f2bf(fmaxf(acc[r] + bj, 0.f));
            }
        }
    }
    __syncthreads();

    // ---- L3: K=64 (2 ksteps), N=128 -> 2 ntiles per wave; no relu; masked max
    {
        short8b af[4][2];
        #pragma unroll
        for (int mt = 0; mt < 4; ++mt)
            #pragma unroll
            for (int ks = 0; ks < 2; ++ks)
                af[mt][ks] = ldfrag(&act2[(mt * 16 + lrow) * 72 + ks * 32 + lk8]);
        #pragma unroll
        for (int nti = 0; nti < 2; ++nti) {
            const int nt = w * 2 + nti;
            short8b bf0 = ldfrag(Wt3 + (size_t)(nt * 16 + lrow) * 72 + 0  + lk8);
            short8b bf1 = ldfrag(Wt3 + (size_t)(nt * 16 + lrow) * 72 + 32 + lk8);
            const float bj = b3[nt * 16 + lrow];
            float vm = -3.4e38f;
            #pragma unroll
            for (int mt = 0; mt < 4; ++mt) {
                f32x4 acc = mfma16(af[mt][0], bf0, zz);
                acc = mfma16(af[mt][1], bf1, acc);
                #pragma unroll
                for (int r = 0; r < 4; ++r) {
                    const int m = mt * 16 + rbase + r;
                    if (m < C) vm = fmaxf(vm, acc[r] + bj);
                }
            }
            vm = fmaxf(vm, __shfl_xor(vm, 16));
            vm = fmaxf(vm, __shfl_xor(vm, 32));
            if (lane < 16) h1[(size_t)bm * 128 + nt * 16 + lrow] = f2bf(vm);
        }
    }
}

// Fused dispatch 3: blocks [0,8192) = conv1; blocks [8192,10240) = radius
// stage 2 (needs cpos1/cpos2 only, independent of conv1's h1).
__global__ __launch_bounds__(256) void conv1_rad2_kernel(
    const float* __restrict__ pos, const float* __restrict__ cpos1,
    const int* __restrict__ nbr1, const int* __restrict__ cnt1,
    const ushort* __restrict__ Wt1, const float* __restrict__ b1,
    const ushort* __restrict__ Wt2, const float* __restrict__ b2,
    const ushort* __restrict__ Wt3, const float* __restrict__ b3,
    ushort* __restrict__ h1,
    const float* __restrict__ cpos2, float rr2,
    int* __restrict__ nbr2, int* __restrict__ cnt2) {
    constexpr int    CB   = B_CL * S1CNT;                    // 8192 conv blocks
    constexpr size_t SM_C = (size_t)64 * 72 * 2 * 2 + KNBR * 4;
    constexpr size_t SM_R = (size_t)S1CNT * 8 + 16;
    __shared__ __align__(16) char smem[SM_C > SM_R ? SM_C : SM_R];
    if (blockIdx.x < CB)
        conv1_body(pos, cpos1, nbr1, cnt1, Wt1, b1, Wt2, b2, Wt3, b3, h1,
                   blockIdx.x, smem);
    else
        radius_body<S1CNT>(cpos1, cpos2, S2CNT, rr2, nbr2, cnt2, smem,
                           (int)(blockIdx.x - CB));
}

// ---------------------------------------------------------------------------
// SA2 PointNetConv via MFMA: [131 -> 128 -> 128 -> 256] per centroid, max-agg.
// ---------------------------------------------------------------------------
__device__ __forceinline__ void conv2_body(const ushort* __restrict__ x,     // h1 bf16
                                           const float* __restrict__ ppos,   // cpos1
                                           const float* __restrict__ cpos,   // cpos2
                                           const int* __restrict__ nbr,
                                           const int* __restrict__ cnt,
                                           const ushort* __restrict__ Wt1, const float* __restrict__ b1,
                                           const ushort* __restrict__ Wt2, const float* __restrict__ b2,
                                           const ushort* __restrict__ Wt3, const float* __restrict__ b3,
                                           ushort* __restrict__ h2, int bm) {
    __shared__ ushort act0[64 * 168];    // also reused as act2 [64][136]
    __shared__ ushort act1[64 * 136];
    __shared__ int    snbr[KNBR];
    ushort* act2 = act0;

    const int b   = bm >> 8;             // S2CNT = 256
    const int tid = threadIdx.x;
    const int C   = cnt[bm];

    const float cx = cpos[bm * 3 + 0];
    const float cy = cpos[bm * 3 + 1];
    const float cz = cpos[bm * 3 + 2];

    if (tid < KNBR) snbr[tid] = (tid < C) ? nbr[(size_t)bm * KNBR + tid] : 0;
    __syncthreads();

    for (int e = tid; e < 1024; e += 256) {          // 64 rows x 16 chunks of 8 bf16
        const int k = e >> 4, c = (e & 15) * 8;
        short8b v = {0, 0, 0, 0, 0, 0, 0, 0};
        if (k < C) v = ldfrag(x + ((size_t)b * S1CNT + snbr[k]) * 128 + c);
        *(short8b*)&act0[k * 168 + c] = v;
    }
    if (tid < KNBR) {
        const int k = tid;
        float r0 = 0.f, r1 = 0.f, r2 = 0.f;
        if (k < C) {
            const float* pp = ppos + ((size_t)b * S1CNT + snbr[k]) * 3;
            r0 = pp[0] - cx; r1 = pp[1] - cy; r2 = pp[2] - cz;
        }
        act0[k * 168 + 128] = f2bf(r0);
        act0[k * 168 + 129] = f2bf(r1);
        act0[k * 168 + 130] = f2bf(r2);
        for (int c = 131; c < 160; ++c) act0[k * 168 + c] = 0;
    }
    __syncthreads();

    const int lane = tid & 63, w = tid >> 6;
    const int lrow = lane & 15;
    const int lk8  = (lane >> 4) * 8;
    const int rbase = (lane >> 4) * 4;
    const f32x4 zz = {0.f, 0.f, 0.f, 0.f};

    // ---- L1: K=131 (5 ksteps), N=128 -> 2 ntiles per wave
    {
        short8b af[4][5];
        #pragma unroll
        for (int mt = 0; mt < 4; ++mt)
            #pragma unroll
            for (int ks = 0; ks < 5; ++ks)
                af[mt][ks] = ldfrag(&act0[(mt * 16 + lrow) * 168 + ks * 32 + lk8]);
        #pragma unroll
        for (int nti = 0; nti < 2; ++nti) {
            const int nt = w * 2 + nti;
            f32x4 acc[4] = {zz, zz, zz, zz};
            #pragma unroll
            for (int ks = 0; ks < 5; ++ks) {
                short8b bf = ldfrag(Wt1 + (size_t)(nt * 16 + lrow) * 168 + ks * 32 + lk8);
                #pragma unroll
                for (int mt = 0; mt < 4; ++mt) acc[mt] = mfma16(af[mt][ks], bf, acc[mt]);
            }
            const float bj = b1[nt * 16 + lrow];
            #pragma unroll
            for (int mt = 0; mt < 4; ++mt)
                #pragma unroll
                for (int r = 0; r < 4; ++r) {
                    const int row = mt * 16 + rbase + r;
                    act1[row * 136 + nt * 16 + lrow] = f2bf(fmaxf(acc[mt][r] + bj, 0.f));
                }
        }
    }
    __syncthreads();

    // ---- L2: K=128 (4 ksteps), N=128 -> 2 ntiles per wave (act1 -> act2)
    {
        short8b af[4][4];
        #pragma unroll
        for (int mt = 0; mt < 4; ++mt)
            #pragma unroll
            for (int ks = 0; ks < 4; ++ks)
                af[mt][ks] = ldfrag(&act1[(mt * 16 + lrow) * 136 + ks * 32 + lk8]);
        #pragma unroll
        for (int nti = 0; nti < 2; ++nti) {
            const int nt = w * 2 + nti;
            f32x4 acc[4] = {zz, zz, zz, zz};
            #pragma unroll
            for (int ks = 0; ks < 4; ++ks) {
                short8b bf = ldfrag(Wt2 + (size_t)(nt * 16 + lrow) * 136 + ks * 32 + lk8);
                #pragma unroll
                for (int mt = 0; mt < 4; ++mt) acc[mt] = mfma16(af[mt][ks], bf, acc[mt]);
            }
            const float bj = b2[nt * 16 + lrow];
            #pragma unroll
            for (int mt = 0; mt < 4; ++mt)
                #pragma unroll
                for (int r = 0; r < 4; ++r) {
                    const int row = mt * 16 + rbase + r;
                    act2[row * 136 + nt * 16 + lrow] = f2bf(fmaxf(acc[mt][r] + bj, 0.f));
                }
        }
    }
    __syncthreads();

    // ---- L3: K=128 (4 ksteps), N=256 -> 4 ntiles per wave; no relu; masked max
    {
        short8b af[4][4];
        #pragma unroll
        for (int mt = 0; mt < 4; ++mt)
            #pragma unroll
            for (int ks = 0; ks < 4; ++ks)
                af[mt][ks] = ldfrag(&act2[(mt * 16 + lrow) * 136 + ks * 32 + lk8]);
        #pragma unroll
        for (int nti = 0; nti < 4; ++nti) {
            const int nt = w * 4 + nti;
            f32x4 acc[4] = {zz, zz, zz, zz};
            #pragma unroll
            for (int ks = 0; ks < 4; ++ks) {
                short8b bf = ldfrag(Wt3 + (size_t)(nt * 16 + lrow) * 136 + ks * 32 + lk8);
                #pragma unroll
                for (int mt = 0; mt < 4; ++mt) acc[mt] = mfma16(af[mt][ks], bf, acc[mt]);
            }
            const float bj = b3[nt * 16 + lrow];
            float vm = -3.4e38f;
            #pragma unroll
            for (int mt = 0; mt < 4; ++mt)
                #pragma unroll
                for (int r = 0; r < 4; ++r) {
                    const int m = mt * 16 + rbase + r;
                    if (m < C) vm = fmaxf(vm, acc[mt][r] + bj);
                }
            vm = fmaxf(vm, __shfl_xor(vm, 16));
            vm = fmaxf(vm, __shfl_xor(vm, 32));
            if (lane < 16) h2[(size_t)bm * 256 + nt * 16 + lrow] = f2bf(vm);
        }
    }
}

// Fused dispatch 4: blocks [0,2048) = conv2; blocks [2048,2080) = gmax init.
__global__ __launch_bounds__(256) void conv2_init_kernel(
    const ushort* __restrict__ x, const float* __restrict__ ppos,
    const float* __restrict__ cpos, const int* __restrict__ nbr,
    const int* __restrict__ cnt,
    const ushort* __restrict__ Wt1, const float* __restrict__ b1,
    const ushort* __restrict__ Wt2, const float* __restrict__ b2,
    const ushort* __restrict__ Wt3, const float* __restrict__ b3,
    ushort* __restrict__ h2, unsigned* __restrict__ gmax) {
    constexpr int CB = B_CL * S2CNT;    // 2048
    if (blockIdx.x < CB)
        conv2_body(x, ppos, cpos, nbr, cnt, Wt1, b1, Wt2, b2, Wt3, b3, h2, blockIdx.x);
    else
        gmax[(size_t)(blockIdx.x - CB) * 256 + threadIdx.x] = 0u;
}

// ---------------------------------------------------------------------------
// Global MLP [259 -> 256 -> 512 -> 1024]: 4 rows per block, VALU fp32,
// atomic-max into order-preserving-encoded uint buffer. h2 input is bf16.
// ---------------------------------------------------------------------------
__device__ __forceinline__ unsigned enc_f32(float f) {
    unsigned u = __float_as_uint(f);
    return (u & 0x80000000u) ? ~u : (u | 0x80000000u);
}

__global__ __launch_bounds__(256) void mlp3_kernel(const ushort* __restrict__ h2,
                                                   const float* __restrict__ cpos2,
                                                   const float* __restrict__ W1, const float* __restrict__ b1,
                                                   const float* __restrict__ W2, const float* __restrict__ b2,
                                                   const float* __restrict__ W3, const float* __restrict__ b3,
                                                   unsigned* __restrict__ gmax) {
    __shared__ float in4[4][260];
    __shared__ float a1s[4][256];
    __shared__ float a2s[4][512];

    const int bm0 = blockIdx.x * 4;      // first of 4 consecutive s-rows (same cloud)
    const int bcl = bm0 >> 8;            // S2CNT = 256
    const int tid = threadIdx.x;

    #pragma unroll
    for (int r = 0; r < 4; ++r) {
        in4[r][tid] = bf2f(h2[(size_t)(bm0 + r) * 256 + tid]);
        if (tid < 3) in4[r][256 + tid] = cpos2[(bm0 + r) * 3 + tid];
    }
    __syncthreads();

    {   // L1: K=259, N=256
        const float bj = b1[tid];
        float acc[4] = {bj, bj, bj, bj};
        for (int i = 0; i < 259; ++i) {
            const float w = W1[i * 256 + tid];
            #pragma unroll
            for (int r = 0; r < 4; ++r) acc[r] += in4[r][i] * w;
        }
        #pragma unroll
        for (int r = 0; r < 4; ++r) a1s[r][tid] = fmaxf(acc[r], 0.f);
    }
    __syncthreads();

    {   // L2: K=256, N=512
        const float bj0 = b2[tid], bj1 = b2[tid + 256];
        float acc0[4] = {bj0, bj0, bj0, bj0};
        float acc1[4] = {bj1, bj1, bj1, bj1};
        for (int i = 0; i < 256; ++i) {
            const float w0 = W2[i * 512 + tid];
            const float w1 = W2[i * 512 + tid + 256];
            #pragma unroll
            for (int r = 0; r < 4; ++r) {
                const float a = a1s[r][i];
                acc0[r] += a * w0;
                acc1[r] += a * w1;
            }
        }
        #pragma unroll
        for (int r = 0; r < 4; ++r) {
            a2s[r][tid]       = fmaxf(acc0[r], 0.f);
            a2s[r][tid + 256] = fmaxf(acc1[r], 0.f);
        }
    }
    __syncthreads();

    {   // L3: K=512, N=1024
        float acc[4][4];
        #pragma unroll
        for (int q = 0; q < 4; ++q) {
            const float bj = b3[tid + 256 * q];
            #pragma unroll
            for (int r = 0; r < 4; ++r) acc[q][r] = bj;
        }
        for (int i = 0; i < 512; ++i) {
            float av[4];
            #pragma unroll
            for (int r = 0; r < 4; ++r) av[r] = a2s[r][i];
            #pragma unroll
            for (int q = 0; q < 4; ++q) {
                const float w = W3[i * 1024 + 256 * q + tid];
                #pragma unroll
                for (int r = 0; r < 4; ++r) acc[q][r] += av[r] * w;
            }
        }
        #pragma unroll
        for (int q = 0; q < 4; ++q)
            #pragma unroll
            for (int r = 0; r < 4; ++r)
                atomicMax(&gmax[(size_t)bcl * 1024 + 256 * q + tid], enc_f32(acc[q][r]));
    }
}

__global__ __launch_bounds__(256) void gmax_decode_kernel(const unsigned* __restrict__ gmax,
                                                          float* __restrict__ out) {
    int t = blockIdx.x * 256 + threadIdx.x;
    unsigned u = gmax[t];
    out[t] = (u & 0x80000000u) ? __uint_as_float(u ^ 0x80000000u) : __uint_as_float(~u);
}

// ---------------------------------------------------------------------------
extern "C" void kernel_launch(void* const* d_in, const int* in_sizes, int n_in,
                              void* d_out, int out_size, void* d_ws, size_t ws_size,
                              hipStream_t stream) {
    (void)in_sizes; (void)n_in; (void)out_size; (void)ws_size;

    const float* pos = (const float*)d_in[0];
    const float* W1a = (const float*)d_in[1];  const float* b1a = (const float*)d_in[2];
    const float* W1b = (const float*)d_in[3];  const float* b1b = (const float*)d_in[4];
    const float* W1c = (const float*)d_in[5];  const float* b1c = (const float*)d_in[6];
    const float* W2a = (const float*)d_in[7];  const float* b2a = (const float*)d_in[8];
    const float* W2b = (const float*)d_in[9];  const float* b2b = (const float*)d_in[10];
    const float* W2c = (const float*)d_in[11]; const float* b2c = (const float*)d_in[12];
    const float* W3a = (const float*)d_in[13]; const float* b3a = (const float*)d_in[14];
    const float* W3b = (const float*)d_in[15]; const float* b3b = (const float*)d_in[16];
    const float* W3c = (const float*)d_in[17]; const float* b3c = (const float*)d_in[18];

    float* out = (float*)d_out;

    char* ws = (char*)d_ws;
    auto alloc = [&](size_t bytes) {
        char* p = ws;
        ws += (bytes + 255) & ~(size_t)255;
        return p;
    };
    float*    cpos1 = (float*)   alloc((size_t)B_CL * S1CNT * 3 * 4);
    int*      nbr1  = (int*)     alloc((size_t)B_CL * S1CNT * KNBR * 4);
    int*      cnt1  = (int*)     alloc((size_t)B_CL * S1CNT * 4);
    ushort*   h1    = (ushort*)  alloc((size_t)B_CL * S1CNT * 128 * 2);
    float*    cpos2 = (float*)   alloc((size_t)B_CL * S2CNT * 3 * 4);
    int*      nbr2  = (int*)     alloc((size_t)B_CL * S2CNT * KNBR * 4);
    int*      cnt2  = (int*)     alloc((size_t)B_CL * S2CNT * 4);
    ushort*   h2    = (ushort*)  alloc((size_t)B_CL * S2CNT * 256 * 2);
    unsigned* gmax  = (unsigned*)alloc((size_t)B_CL * 1024 * 4);
    ushort*   Wt1a  = (ushort*)  alloc((size_t)64  * 40  * 2);
    ushort*   Wt1b  = (ushort*)  alloc((size_t)64  * 72  * 2);
    ushort*   Wt1c  = (ushort*)  alloc((size_t)128 * 72  * 2);
    ushort*   Wt2a  = (ushort*)  alloc((size_t)128 * 168 * 2);
    ushort*   Wt2b  = (ushort*)  alloc((size_t)128 * 136 * 2);
    ushort*   Wt2c  = (ushort*)  alloc((size_t)256 * 136 * 2);

    const float RR1 = (float)(0.2 * 0.2);
    const float RR2 = (float)(0.4 * 0.4);

    // 1: FPS stage 1 (8 blocks x 512) + 6 weight-prep blocks
    fps1_wprep_kernel<<<B_CL + 6, 512, 0, stream>>>(pos, cpos1,
                                                    W1a, Wt1a, W1b, Wt1b, W1c, Wt1c,
                                                    W2a, Wt2a, W2b, Wt2b, W2c, Wt2c);
    // 2: radius stage 1 + FPS stage 2
    radius1_fps2_kernel<<<B_CL * S1CNT + B_CL, 256, 0, stream>>>(pos, cpos1, RR1,
                                                                 nbr1, cnt1, cpos2);
    // 3: conv1 + radius stage 2
    conv1_rad2_kernel<<<B_CL * S1CNT + B_CL * S2CNT, 256, 0, stream>>>(
        pos, cpos1, nbr1, cnt1, Wt1a, b1a, Wt1b, b1b, Wt1c, b1c, h1,
        cpos2, RR2, nbr2, cnt2);
    // 4: conv2 + gmax init
    conv2_init_kernel<<<B_CL * S2CNT + (B_CL * 1024) / 256, 256, 0, stream>>>(
        h1, cpos1, cpos2, nbr2, cnt2, Wt2a, b2a, Wt2b, b2b, Wt2c, b2c, h2, gmax);
    // 5: global MLP + max pool
    mlp3_kernel<<<(B_CL * S2CNT) / 4, 256, 0, stream>>>(h2, cpos2,
                                                        W3a, b3a, W3b, b3b, W3c, b3c, gmax);
    // 6: decode
    gmax_decode_kernel<<<(B_CL * 1024) / 256, 256, 0, stream>>>(gmax, out);
}

// Round 11
// 947.380 us; speedup vs baseline: 1.2458x; 1.0416x over previous
//
#include <hip/hip_runtime.h>
#include <hip/hip_bf16.h>
#include <cstdint>
#include <cstddef>

// Problem constants (match reference)
#define B_CL   8
#define NPTS   2048
#define S1CNT  1024
#define S2CNT  256
#define KNBR   64

typedef unsigned short ushort;
typedef __attribute__((ext_vector_type(8))) short short8b;  // 8 bf16 = MFMA A/B frag
typedef __attribute__((ext_vector_type(4))) float f32x4;    // MFMA C/D frag

__device__ __forceinline__ ushort f2bf(float f) {
    union { __hip_bfloat16 h; ushort u; } v;
    v.h = __float2bfloat16(f);
    return v.u;
}
__device__ __forceinline__ float bf2f(ushort u) {
    return __uint_as_float(((unsigned)u) << 16);
}
__device__ __forceinline__ short8b ldfrag(const ushort* p) {
    return *(const short8b*)p;
}
__device__ __forceinline__ f32x4 mfma16(short8b a, short8b b, f32x4 c) {
    return __builtin_amdgcn_mfma_f32_16x16x32_bf16(a, b, c, 0, 0, 0);
}

// Exact f32 squared distance in the reference's summation order.
__device__ __forceinline__ float dist2_exact(float ax, float ay, float az,
                                             float bx, float by, float bz) {
    float dx = __fsub_rn(ax, bx);
    float dy = __fsub_rn(ay, by);
    float dz = __fsub_rn(az, bz);
    return __fadd_rn(__fadd_rn(__fmul_rn(dx, dx), __fmul_rn(dy, dy)), __fmul_rn(dz, dz));
}

// 64-lane max-reduce of a u64 key via DPP (single combined chain: value+index
// tie-break in one u64 compare per step). Result valid in lane 63.
__device__ __forceinline__ unsigned long long wave_max_u64(unsigned long long k) {
#define DPP_STEP(CTRL) {                                                            \
    unsigned lo = (unsigned)k, hi = (unsigned)(k >> 32);                            \
    unsigned nlo = (unsigned)__builtin_amdgcn_update_dpp((int)lo, (int)lo, CTRL,    \
                                                         0xf, 0xf, false);          \
    unsigned nhi = (unsigned)__builtin_amdgcn_update_dpp((int)hi, (int)hi, CTRL,    \
                                                         0xf, 0xf, false);          \
    unsigned long long nk = ((unsigned long long)nhi << 32) | nlo;                  \
    if (nk > k) k = nk;                                                             \
}
    DPP_STEP(0x111);  // row_shr:1
    DPP_STEP(0x112);  // row_shr:2
    DPP_STEP(0x114);  // row_shr:4
    DPP_STEP(0x118);  // row_shr:8
    DPP_STEP(0x142);  // row_bcast:15
    DPP_STEP(0x143);  // row_bcast:31
#undef DPP_STEP
    return k;
}

// ---------------------------------------------------------------------------
// Farthest point sampling v3. One cloud per block, NT threads (NT/64 waves).
// Per iteration (single LDS round trip, single u64 DPP chain, one readlane):
//   update d + local argmax (PPT pts/thread)
//   wave reduce: u64 (d2,~idx) DPP max chain -> lane 63 -> readlane(low32)
//     broadcasts winner index -> the lane OWNING that index (unique) writes
//     key + its coords to the wave's parity LDS slot
//   raw lgkmcnt barrier (no vmem drain), all threads resolve W wave winners
//   tid==0 streams the block winner to cpos (fire-and-forget vmem).
// ---------------------------------------------------------------------------
template <int N, int S, int NT>
__device__ __forceinline__ void fps_body2(const float* __restrict__ pos,
                                          float* __restrict__ cpos,
                                          int b, char* smem) {
    constexpr int PPT = N / NT;
    constexpr int W   = NT / 64;
    unsigned long long* kbuf = (unsigned long long*)smem;                // [2][W]
    float4* cbuf = (float4*)(smem + 2 * W * sizeof(unsigned long long)); // [2][W]

    const int tid = threadIdx.x;
    const int wid = tid >> 6;
    const float* P = pos + (size_t)b * N * 3;

    float ox[PPT], oy[PPT], oz[PPT], d[PPT];
    #pragma unroll
    for (int j = 0; j < PPT; ++j) {
        const int idx = tid + NT * j;
        ox[j] = P[idx * 3 + 0];
        oy[j] = P[idx * 3 + 1];
        oz[j] = P[idx * 3 + 2];
        d[j]  = 1e30f;
    }
    float cx = P[0], cy = P[1], cz = P[2];
    if (tid == 0) {
        float* cp = cpos + (size_t)b * S * 3;
        cp[0] = cx; cp[1] = cy; cp[2] = cz;
    }

    for (int i = 1; i < S; ++i) {
        float bv = -1.0f;
        int   bi = 0;
        #pragma unroll
        for (int j = 0; j < PPT; ++j) {
            const int idx = tid + NT * j;
            const float dd = dist2_exact(ox[j], oy[j], oz[j], cx, cy, cz);
            const float nd = fminf(d[j], dd);
            d[j] = nd;
            if (nd > bv) { bv = nd; bi = idx; }
        }
        // pack (d2, ~idx): u64 max == (max d2, then min idx); d2>=0 so the f32
        // bit pattern is order-preserving. Single chain, result in lane 63.
        const unsigned long long key =
            ((unsigned long long)__float_as_uint(bv) << 32) | (unsigned)(~bi);
        const unsigned long long kmax = wave_max_u64(key);
        // broadcast the wave-winning point index from lane 63 (low 32 bits)
        const int wbi = ~__builtin_amdgcn_readlane((int)(unsigned)kmax, 63);

        const int par = i & 1;
        if (bi == wbi) {
            // unique owner lane of the wave-winning point (indices disjoint)
            const int jw = bi / NT;
            float wx = ox[0], wy = oy[0], wz = oz[0];
            #pragma unroll
            for (int j = 1; j < PPT; ++j)
                if (jw == j) { wx = ox[j]; wy = oy[j]; wz = oz[j]; }
            kbuf[par * W + wid] = key;
            cbuf[par * W + wid] = make_float4(wx, wy, wz, 0.f);
        }
        // raw barrier: LDS-only wait; global stores never enter the sync path
        asm volatile("s_waitcnt lgkmcnt(0)" ::: "memory");
        __builtin_amdgcn_s_barrier();
        __builtin_amdgcn_sched_barrier(0);

        // resolve W wave winners: load all slots first (pipelined broadcast
        // reads), then one compare chain
        unsigned long long kr[W];
        float4 cr[W];
        #pragma unroll
        for (int w2 = 0; w2 < W; ++w2) {
            kr[w2] = kbuf[par * W + w2];
            cr[w2] = cbuf[par * W + w2];
        }
        unsigned long long kk = kr[0];
        float4 cc = cr[0];
        #pragma unroll
        for (int w2 = 1; w2 < W; ++w2)
            if (kr[w2] > kk) { kk = kr[w2]; cc = cr[w2]; }
        cx = cc.x; cy = cc.y; cz = cc.z;
        // single designated writer exports the BLOCK winner
        if (tid == 0) {
            float* cp = cpos + ((size_t)b * S + i) * 3;
            cp[0] = cx; cp[1] = cy; cp[2] = cz;   // fire-and-forget (vmem)
        }
    }
}

// ---------------------------------------------------------------------------
// Radius neighbor search body (bit-exact top_k semantics), smem passed in.
// 256 threads.
// ---------------------------------------------------------------------------
template <int N>
__device__ __forceinline__ void radius_body(const float* __restrict__ pos,
                                            const float* __restrict__ cpos,
                                            int M, float rr,
                                            int* __restrict__ nbr,
                                            int* __restrict__ cnt,
                                            char* smem, int bm) {
    unsigned long long* list = (unsigned long long*)smem;
    int* c_sh = (int*)(smem + (size_t)N * 8);

    const int b   = bm / M;
    const int tid = threadIdx.x;
    const float* P = pos + (size_t)b * N * 3;

    const float cx = cpos[bm * 3 + 0];
    const float cy = cpos[bm * 3 + 1];
    const float cz = cpos[bm * 3 + 2];

    if (tid == 0) *c_sh = 0;
    __syncthreads();

    for (int i = tid; i < N; i += 256) {
        float d2 = dist2_exact(cx, cy, cz, P[i * 3], P[i * 3 + 1], P[i * 3 + 2]);
        if (d2 <= rr) {
            int slot = atomicAdd(c_sh, 1);
            list[slot] = ((unsigned long long)__float_as_uint(d2) << 32) | (unsigned int)i;
        }
    }
    __syncthreads();
    int C = *c_sh;

    if (C <= KNBR) {
        if (tid < C) nbr[(size_t)bm * KNBR + tid] = (int)(list[tid] & 0xffffffffu);
        if (tid == 0) cnt[bm] = C;
        return;
    }

    int P2 = 1;
    while (P2 < C) P2 <<= 1;
    for (int i = C + tid; i < P2; i += 256) list[i] = ~0ULL;
    __syncthreads();
    for (int k = 2; k <= P2; k <<= 1) {
        for (int j = k >> 1; j > 0; j >>= 1) {
            for (int i = tid; i < P2; i += 256) {
                int l = i ^ j;
                if (l > i) {
                    unsigned long long a = list[i], bb = list[l];
                    bool up = ((i & k) == 0);
                    if ((a > bb) == up) { list[i] = bb; list[l] = a; }
                }
            }
            __syncthreads();
        }
    }
    if (tid < KNBR) nbr[(size_t)bm * KNBR + tid] = (int)(list[tid] & 0xffffffffu);
    if (tid == 0) cnt[bm] = KNBR;
}

// ---------------------------------------------------------------------------
// Weight prep body: W [K][N] f32 -> Wt [N][Kpad] bf16, grid-stride 256 thr.
// ---------------------------------------------------------------------------
__device__ __forceinline__ void wprep_body(const float* __restrict__ W,
                                           ushort* __restrict__ Wt,
                                           int K, int N, int Kpad) {
    const int total = N * Kpad;
    for (int e = threadIdx.x; e < total; e += 256) {
        const int n = e / Kpad, k = e - n * Kpad;
        Wt[e] = (k < K) ? f2bf(W[(size_t)k * N + n]) : (ushort)0;
    }
}

// ---------------------------------------------------------------------------
// Fused dispatch 1: blocks [0,8) = FPS stage 1 (256 thr, 4 waves); blocks
// [8,14) = bf16 weight transposes (fill idle CUs during the serial FPS).
// ---------------------------------------------------------------------------
__global__ __launch_bounds__(256) void fps1_wprep_kernel(
    const float* __restrict__ pos, float* __restrict__ cpos1,
    const float* __restrict__ W1a, ushort* __restrict__ Wt1a,
    const float* __restrict__ W1b, ushort* __restrict__ Wt1b,
    const float* __restrict__ W1c, ushort* __restrict__ Wt1c,
    const float* __restrict__ W2a, ushort* __restrict__ Wt2a,
    const float* __restrict__ W2b, ushort* __restrict__ Wt2b,
    const float* __restrict__ W2c, ushort* __restrict__ Wt2c) {
    __shared__ __align__(16) char smem[2 * 4 * 8 + 2 * 4 * 16];
    const int bx = blockIdx.x;
    if (bx < B_CL) { fps_body2<NPTS, S1CNT, 256>(pos, cpos1, bx, smem); return; }
    switch (bx - B_CL) {
        case 0: wprep_body(W1a, Wt1a, 3,   64,  40);  break;
        case 1: wprep_body(W1b, Wt1b, 64,  64,  72);  break;
        case 2: wprep_body(W1c, Wt1c, 64,  128, 72);  break;
        case 3: wprep_body(W2a, Wt2a, 131, 128, 168); break;
        case 4: wprep_body(W2b, Wt2b, 128, 128, 136); break;
        case 5: wprep_body(W2c, Wt2c, 128, 256, 136); break;
        default: break;
    }
}

// ---------------------------------------------------------------------------
// Fused dispatch 2: blocks [0, 8192) = radius stage 1; blocks [8192, 8200) =
// FPS stage 2 (needs only cpos1; hides inside this dispatch).
// ---------------------------------------------------------------------------
__global__ __launch_bounds__(256) void radius1_fps2_kernel(const float* __restrict__ pos,
                                                           const float* __restrict__ cpos1,
                                                           float rr1,
                                                           int* __restrict__ nbr1,
                                                           int* __restrict__ cnt1,
                                                           float* __restrict__ cpos2) {
    constexpr int    RB   = B_CL * S1CNT;                 // 8192 radius blocks
    constexpr size_t SM_R = (size_t)NPTS * 8 + 16;        // 16.4 KB
    __shared__ __align__(16) char smem[SM_R];
    if (blockIdx.x < RB)
        radius_body<NPTS>(pos, cpos1, S1CNT, rr1, nbr1, cnt1, smem, blockIdx.x);
    else
        fps_body2<S1CNT, S2CNT, 256>(cpos1, cpos2, (int)(blockIdx.x - RB), smem);
}

// ---------------------------------------------------------------------------
// SA1 PointNetConv via MFMA: [3 -> 64 -> 64 -> 128] per centroid, max-agg.
// ---------------------------------------------------------------------------
__device__ __forceinline__ void conv1_body(const float* __restrict__ pos,
                                           const float* __restrict__ cpos,
                                           const int* __restrict__ nbr,
                                           const int* __restrict__ cnt,
                                           const ushort* __restrict__ Wt1, const float* __restrict__ b1,
                                           const ushort* __restrict__ Wt2, const float* __restrict__ b2,
                                           const ushort* __restrict__ Wt3, const float* __restrict__ b3,
                                           ushort* __restrict__ h1,
                                           int bm, char* smem) {
    ushort* act1 = (ushort*)smem;            // [64*72]
    ushort* act2 = act1 + 64 * 72;           // [64*72]
    int*    snbr = (int*)(act2 + 64 * 72);   // [KNBR]

    const int b   = bm >> 10;            // S1CNT = 1024
    const int tid = threadIdx.x;
    const int C   = cnt[bm];

    const float cx = cpos[bm * 3 + 0];
    const float cy = cpos[bm * 3 + 1];
    const float cz = cpos[bm * 3 + 2];

    if (tid < KNBR) snbr[tid] = (tid < C) ? nbr[(size_t)bm * KNBR + tid] : 0;
    __syncthreads();

    const int lane = tid & 63, w = tid >> 6;
    const int lrow = lane & 15;          // frag row/col within 16
    const int lk8  = (lane >> 4) * 8;    // frag k-base
    const int rbase = (lane >> 4) * 4;   // C-frag row base
    const f32x4 zz = {0.f, 0.f, 0.f, 0.f};

    // ---- build A0 frags in registers (K=3, k>=3 zero; lanes with k-base>=8 zero)
    short8b a0[4];
    #pragma unroll
    for (int mt = 0; mt < 4; ++mt) {
        short8b a = {0, 0, 0, 0, 0, 0, 0, 0};
        if (lane < 16) {
            const int nb = snbr[mt * 16 + lrow];
            const float* pp = pos + ((size_t)b * NPTS + nb) * 3;
            a[0] = (short)f2bf(pp[0] - cx);
            a[1] = (short)f2bf(pp[1] - cy);
            a[2] = (short)f2bf(pp[2] - cz);
        }
        a0[mt] = a;
    }

    // ---- L1: K=3 (1 kstep), N=64 -> 1 ntile per wave
    {
        const int nt = w;
        short8b bf = ldfrag(Wt1 + (size_t)(nt * 16 + lrow) * 40 + lk8);
        const float bj = b1[nt * 16 + lrow];
        #pragma unroll
        for (int mt = 0; mt < 4; ++mt) {
            f32x4 acc = mfma16(a0[mt], bf, zz);
            #pragma unroll
            for (int r = 0; r < 4; ++r) {
                const int row = mt * 16 + rbase + r;
                act1[row * 72 + nt * 16 + lrow] = f2bf(fmaxf(acc[r] + bj, 0.f));
            }
        }
    }
    __syncthreads();

    // ---- L2: K=64 (2 ksteps), N=64 -> 1 ntile per wave
    {
        short8b af[4][2];
        #pragma unroll
        for (int mt = 0; mt < 4; ++mt)
            #pragma unroll
            for (int ks = 0; ks < 2; ++ks)
                af[mt][ks] = ldfrag(&act1[(mt * 16 + lrow) * 72 + ks * 32 + lk8]);
        const int nt = w;
        short8b bf0 = ldfrag(Wt2 + (size_t)(nt * 16 + lrow) * 72 + 0  + lk8);
        short8b bf1 = ldfrag(Wt2 + (size_t)(nt * 16 + lrow) * 72 + 32 + lk8);
        const float bj = b2[nt * 16 + lrow];
        #pragma unroll
        for (int mt = 0; mt < 4; ++mt) {
            f32x4 acc = mfma16(af[mt][0], bf0, zz);
            acc = mfma16(af[mt][1], bf1, acc);
            #pragma unroll
            for (int r = 0; r < 4; ++r) {
                const int row = mt * 16 + rbase + r;
                act2[row * 72 + nt * 16 + lrow] = f2bf(fmaxf(acc[r] + bj, 0.f));
            }
        }
    }
    __syncthreads();

    // ---- L3: K=64 (2 ksteps), N=128 -> 2 ntiles per wave; no relu; masked max
    {
        short8b af[4][2];
        #pragma unroll
        for (int mt = 0; mt < 4; ++mt)
            #pragma unroll
            for (int ks = 0; ks < 2; ++ks)
                af[mt][ks] = ldfrag(&act2[(mt * 16 + lrow) * 72 + ks * 32 + lk8]);
        #pragma unroll
        for (int nti = 0; nti < 2; ++nti) {
            const int nt = w * 2 + nti;
            short8b bf0 = ldfrag(Wt3 + (size_t)(nt * 16 + lrow) * 72 + 0  + lk8);
            short8b bf1 = ldfrag(Wt3 + (size_t)(nt * 16 + lrow) * 72 + 32 + lk8);
            const float bj = b3[nt * 16 + lrow];
            float vm = -3.4e38f;
            #pragma unroll
            for (int mt = 0; mt < 4; ++mt) {
                f32x4 acc = mfma16(af[mt][0], bf0, zz);
                acc = mfma16(af[mt][1], bf1, acc);
                #pragma unroll
                for (int r = 0; r < 4; ++r) {
                    const int m = mt * 16 + rbase + r;
                    if (m < C) vm = fmaxf(vm, acc[r] + bj);
                }
            }
            vm = fmaxf(vm, __shfl_xor(vm, 16));
            vm = fmaxf(vm, __shfl_xor(vm, 32));
            if (lane < 16) h1[(size_t)bm * 128 + nt * 16 + lrow] = f2bf(vm);
        }
    }
}

// Fused dispatch 3: blocks [0,8192) = conv1; blocks [8192,10240) = radius
// stage 2 (needs cpos1/cpos2 only, independent of conv1's h1).
__global__ __launch_bounds__(256) void conv1_rad2_kernel(
    const float* __restrict__ pos, const float* __restrict__ cpos1,
    const int* __restrict__ nbr1, const int* __restrict__ cnt1,
    const ushort* __restrict__ Wt1, const float* __restrict__ b1,
    const ushort* __restrict__ Wt2, const float* __restrict__ b2,
    const ushort* __restrict__ Wt3, const float* __restrict__ b3,
    ushort* __restrict__ h1,
    const float* __restrict__ cpos2, float rr2,
    int* __restrict__ nbr2, int* __restrict__ cnt2) {
    constexpr int    CB   = B_CL * S1CNT;                    // 8192 conv blocks
    constexpr size_t SM_C = (size_t)64 * 72 * 2 * 2 + KNBR * 4;
    constexpr size_t SM_R = (size_t)S1CNT * 8 + 16;
    __shared__ __align__(16) char smem[SM_C > SM_R ? SM_C : SM_R];
    if (blockIdx.x < CB)
        conv1_body(pos, cpos1, nbr1, cnt1, Wt1, b1, Wt2, b2, Wt3, b3, h1,
                   blockIdx.x, smem);
    else
        radius_body<S1CNT>(cpos1, cpos2, S2CNT, rr2, nbr2, cnt2, smem,
                           (int)(blockIdx.x - CB));
}

// ---------------------------------------------------------------------------
// SA2 PointNetConv via MFMA: [131 -> 128 -> 128 -> 256] per centroid, max-agg.
// ---------------------------------------------------------------------------
__device__ __forceinline__ void conv2_body(const ushort* __restrict__ x,     // h1 bf16
                                           const float* __restrict__ ppos,   // cpos1
                                           const float* __restrict__ cpos,   // cpos2
                                           const int* __restrict__ nbr,
                                           const int* __restrict__ cnt,
                                           const ushort* __restrict__ Wt1, const float* __restrict__ b1,
                                           const ushort* __restrict__ Wt2, const float* __restrict__ b2,
                                           const ushort* __restrict__ Wt3, const float* __restrict__ b3,
                                           ushort* __restrict__ h2, int bm) {
    __shared__ ushort act0[64 * 168];    // also reused as act2 [64][136]
    __shared__ ushort act1[64 * 136];
    __shared__ int    snbr[KNBR];
    ushort* act2 = act0;

    const int b   = bm >> 8;             // S2CNT = 256
    const int tid = threadIdx.x;
    const int C   = cnt[bm];

    const float cx = cpos[bm * 3 + 0];
    const float cy = cpos[bm * 3 + 1];
    const float cz = cpos[bm * 3 + 2];

    if (tid < KNBR) snbr[tid] = (tid < C) ? nbr[(size_t)bm * KNBR + tid] : 0;
    __syncthreads();

    for (int e = tid; e < 1024; e += 256) {          // 64 rows x 16 chunks of 8 bf16
        const int k = e >> 4, c = (e & 15) * 8;
        short8b v = {0, 0, 0, 0, 0, 0, 0, 0};
        if (k < C) v = ldfrag(x + ((size_t)b * S1CNT + snbr[k]) * 128 + c);
        *(short8b*)&act0[k * 168 + c] = v;
    }
    if (tid < KNBR) {
        const int k = tid;
        float r0 = 0.f, r1 = 0.f, r2 = 0.f;
        if (k < C) {
            const float* pp = ppos + ((size_t)b * S1CNT + snbr[k]) * 3;
            r0 = pp[0] - cx; r1 = pp[1] - cy; r2 = pp[2] - cz;
        }
        act0[k * 168 + 128] = f2bf(r0);
        act0[k * 168 + 129] = f2bf(r1);
        act0[k * 168 + 130] = f2bf(r2);
        for (int c = 131; c < 160; ++c) act0[k * 168 + c] = 0;
    }
    __syncthreads();

    const int lane = tid & 63, w = tid >> 6;
    const int lrow = lane & 15;
    const int lk8  = (lane >> 4) * 8;
    const int rbase = (lane >> 4) * 4;
    const f32x4 zz = {0.f, 0.f, 0.f, 0.f};

    // ---- L1: K=131 (5 ksteps), N=128 -> 2 ntiles per wave
    {
        short8b af[4][5];
        #pragma unroll
        for (int mt = 0; mt < 4; ++mt)
            #pragma unroll
            for (int ks = 0; ks < 5; ++ks)
                af[mt][ks] = ldfrag(&act0[(mt * 16 + lrow) * 168 + ks * 32 + lk8]);
        #pragma unroll
        for (int nti = 0; nti < 2; ++nti) {
            const int nt = w * 2 + nti;
            f32x4 acc[4] = {zz, zz, zz, zz};
            #pragma unroll
            for (int ks = 0; ks < 5; ++ks) {
                short8b bf = ldfrag(Wt1 + (size_t)(nt * 16 + lrow) * 168 + ks * 32 + lk8);
                #pragma unroll
                for (int mt = 0; mt < 4; ++mt) acc[mt] = mfma16(af[mt][ks], bf, acc[mt]);
            }
            const float bj = b1[nt * 16 + lrow];
            #pragma unroll
            for (int mt = 0; mt < 4; ++mt)
                #pragma unroll
                for (int r = 0; r < 4; ++r) {
                    const int row = mt * 16 + rbase + r;
                    act1[row * 136 + nt * 16 + lrow] = f2bf(fmaxf(acc[mt][r] + bj, 0.f));
                }
        }
    }
    __syncthreads();

    // ---- L2: K=128 (4 ksteps), N=128 -> 2 ntiles per wave (act1 -> act2)
    {
        short8b af[4][4];
        #pragma unroll
        for (int mt = 0; mt < 4; ++mt)
            #pragma unroll
            for (int ks = 0; ks < 4; ++ks)
                af[mt][ks] = ldfrag(&act1[(mt * 16 + lrow) * 136 + ks * 32 + lk8]);
        #pragma unroll
        for (int nti = 0; nti < 2; ++nti) {
            const int nt = w * 2 + nti;
            f32x4 acc[4] = {zz, zz, zz, zz};
            #pragma unroll
            for (int ks = 0; ks < 4; ++ks) {
                short8b bf = ldfrag(Wt2 + (size_t)(nt * 16 + lrow) * 136 + ks * 32 + lk8);
                #pragma unroll
                for (int mt = 0; mt < 4; ++mt) acc[mt] = mfma16(af[mt][ks], bf, acc[mt]);
            }
            const float bj = b2[nt * 16 + lrow];
            #pragma unroll
            for (int mt = 0; mt < 4; ++mt)
                #pragma unroll
                for (int r = 0; r < 4; ++r) {
                    const int row = mt * 16 + rbase + r;
                    act2[row * 136 + nt * 16 + lrow] = f2bf(fmaxf(acc[mt][r] + bj, 0.f));
                }
        }
    }
    __syncthreads();

    // ---- L3: K=128 (4 ksteps), N=256 -> 4 ntiles per wave; no relu; masked max
    {
        short8b af[4][4];
        #pragma unroll
        for (int mt = 0; mt < 4; ++mt)
            #pragma unroll
            for (int ks = 0; ks < 4; ++ks)
                af[mt][ks] = ldfrag(&act2[(mt * 16 + lrow) * 136 + ks * 32 + lk8]);
        #pragma unroll
        for (int nti = 0; nti < 4; ++nti) {
            const int nt = w * 4 + nti;
            f32x4 acc[4] = {zz, zz, zz, zz};
            #pragma unroll
            for (int ks = 0; ks < 4; ++ks) {
                short8b bf = ldfrag(Wt3 + (size_t)(nt * 16 + lrow) * 136 + ks * 32 + lk8);
                #pragma unroll
                for (int mt = 0; mt < 4; ++mt) acc[mt] = mfma16(af[mt][ks], bf, acc[mt]);
            }
            const float bj = b3[nt * 16 + lrow];
            float vm = -3.4e38f;
            #pragma unroll
            for (int mt = 0; mt < 4; ++mt)
                #pragma unroll
                for (int r = 0; r < 4; ++r) {
                    const int m = mt * 16 + rbase + r;
                    if (m < C) vm = fmaxf(vm, acc[mt][r] + bj);
                }
            vm = fmaxf(vm, __shfl_xor(vm, 16));
            vm = fmaxf(vm, __shfl_xor(vm, 32));
            if (lane < 16) h2[(size_t)bm * 256 + nt * 16 + lrow] = f2bf(vm);
        }
    }
}

// Fused dispatch 4: blocks [0,2048) = conv2; blocks [2048,2080) = gmax init.
__global__ __launch_bounds__(256) void conv2_init_kernel(
    const ushort* __restrict__ x, const float* __restrict__ ppos,
    const float* __restrict__ cpos, const int* __restrict__ nbr,
    const int* __restrict__ cnt,
    const ushort* __restrict__ Wt1, const float* __restrict__ b1,
    const ushort* __restrict__ Wt2, const float* __restrict__ b2,
    const ushort* __restrict__ Wt3, const float* __restrict__ b3,
    ushort* __restrict__ h2, unsigned* __restrict__ gmax) {
    constexpr int CB = B_CL * S2CNT;    // 2048
    if (blockIdx.x < CB)
        conv2_body(x, ppos, cpos, nbr, cnt, Wt1, b1, Wt2, b2, Wt3, b3, h2, blockIdx.x);
    else
        gmax[(size_t)(blockIdx.x - CB) * 256 + threadIdx.x] = 0u;
}

// ---------------------------------------------------------------------------
// Global MLP [259 -> 256 -> 512 -> 1024]: 4 rows per block, VALU fp32,
// atomic-max into order-preserving-encoded uint buffer. h2 input is bf16.
// ---------------------------------------------------------------------------
__device__ __forceinline__ unsigned enc_f32(float f) {
    unsigned u = __float_as_uint(f);
    return (u & 0x80000000u) ? ~u : (u | 0x80000000u);
}

__global__ __launch_bounds__(256) void mlp3_kernel(const ushort* __restrict__ h2,
                                                   const float* __restrict__ cpos2,
                                                   const float* __restrict__ W1, const float* __restrict__ b1,
                                                   const float* __restrict__ W2, const float* __restrict__ b2,
                                                   const float* __restrict__ W3, const float* __restrict__ b3,
                                                   unsigned* __restrict__ gmax) {
    __shared__ float in4[4][260];
    __shared__ float a1s[4][256];
    __shared__ float a2s[4][512];

    const int bm0 = blockIdx.x * 4;      // first of 4 consecutive s-rows (same cloud)
    const int bcl = bm0 >> 8;            // S2CNT = 256
    const int tid = threadIdx.x;

    #pragma unroll
    for (int r = 0; r < 4; ++r) {
        in4[r][tid] = bf2f(h2[(size_t)(bm0 + r) * 256 + tid]);
        if (tid < 3) in4[r][256 + tid] = cpos2[(bm0 + r) * 3 + tid];
    }
    __syncthreads();

    {   // L1: K=259, N=256
        const float bj = b1[tid];
        float acc[4] = {bj, bj, bj, bj};
        for (int i = 0; i < 259; ++i) {
            const float w = W1[i * 256 + tid];
            #pragma unroll
            for (int r = 0; r < 4; ++r) acc[r] += in4[r][i] * w;
        }
        #pragma unroll
        for (int r = 0; r < 4; ++r) a1s[r][tid] = fmaxf(acc[r], 0.f);
    }
    __syncthreads();

    {   // L2: K=256, N=512
        const float bj0 = b2[tid], bj1 = b2[tid + 256];
        float acc0[4] = {bj0, bj0, bj0, bj0};
        float acc1[4] = {bj1, bj1, bj1, bj1};
        for (int i = 0; i < 256; ++i) {
            const float w0 = W2[i * 512 + tid];
            const float w1 = W2[i * 512 + tid + 256];
            #pragma unroll
            for (int r = 0; r < 4; ++r) {
                const float a = a1s[r][i];
                acc0[r] += a * w0;
                acc1[r] += a * w1;
            }
        }
        #pragma unroll
        for (int r = 0; r < 4; ++r) {
            a2s[r][tid]       = fmaxf(acc0[r], 0.f);
            a2s[r][tid + 256] = fmaxf(acc1[r], 0.f);
        }
    }
    __syncthreads();

    {   // L3: K=512, N=1024
        float acc[4][4];
        #pragma unroll
        for (int q = 0; q < 4; ++q) {
            const float bj = b3[tid + 256 * q];
            #pragma unroll
            for (int r = 0; r < 4; ++r) acc[q][r] = bj;
        }
        for (int i = 0; i < 512; ++i) {
            float av[4];
            #pragma unroll
            for (int r = 0; r < 4; ++r) av[r] = a2s[r][i];
            #pragma unroll
            for (int q = 0; q < 4; ++q) {
                const float w = W3[i * 1024 + 256 * q + tid];
                #pragma unroll
                for (int r = 0; r < 4; ++r) acc[q][r] += av[r] * w;
            }
        }
        #pragma unroll
        for (int q = 0; q < 4; ++q)
            #pragma unroll
            for (int r = 0; r < 4; ++r)
                atomicMax(&gmax[(size_t)bcl * 1024 + 256 * q + tid], enc_f32(acc[q][r]));
    }
}

__global__ __launch_bounds__(256) void gmax_decode_kernel(const unsigned* __restrict__ gmax,
                                                          float* __restrict__ out) {
    int t = blockIdx.x * 256 + threadIdx.x;
    unsigned u = gmax[t];
    out[t] = (u & 0x80000000u) ? __uint_as_float(u ^ 0x80000000u) : __uint_as_float(~u);
}

// ---------------------------------------------------------------------------
extern "C" void kernel_launch(void* const* d_in, const int* in_sizes, int n_in,
                              void* d_out, int out_size, void* d_ws, size_t ws_size,
                              hipStream_t stream) {
    (void)in_sizes; (void)n_in; (void)out_size; (void)ws_size;

    const float* pos = (const float*)d_in[0];
    const float* W1a = (const float*)d_in[1];  const float* b1a = (const float*)d_in[2];
    const float* W1b = (const float*)d_in[3];  const float* b1b = (const float*)d_in[4];
    const float* W1c = (const float*)d_in[5];  const float* b1c = (const float*)d_in[6];
    const float* W2a = (const float*)d_in[7];  const float* b2a = (const float*)d_in[8];
    const float* W2b = (const float*)d_in[9];  const float* b2b = (const float*)d_in[10];
    const float* W2c = (const float*)d_in[11]; const float* b2c = (const float*)d_in[12];
    const float* W3a = (const float*)d_in[13]; const float* b3a = (const float*)d_in[14];
    const float* W3b = (const float*)d_in[15]; const float* b3b = (const float*)d_in[16];
    const float* W3c = (const float*)d_in[17]; const float* b3c = (const float*)d_in[18];

    float* out = (float*)d_out;

    char* ws = (char*)d_ws;
    auto alloc = [&](size_t bytes) {
        char* p = ws;
        ws += (bytes + 255) & ~(size_t)255;
        return p;
    };
    float*    cpos1 = (float*)   alloc((size_t)B_CL * S1CNT * 3 * 4);
    int*      nbr1  = (int*)     alloc((size_t)B_CL * S1CNT * KNBR * 4);
    int*      cnt1  = (int*)     alloc((size_t)B_CL * S1CNT * 4);
    ushort*   h1    = (ushort*)  alloc((size_t)B_CL * S1CNT * 128 * 2);
    float*    cpos2 = (float*)   alloc((size_t)B_CL * S2CNT * 3 * 4);
    int*      nbr2  = (int*)     alloc((size_t)B_CL * S2CNT * KNBR * 4);
    int*      cnt2  = (int*)     alloc((size_t)B_CL * S2CNT * 4);
    ushort*   h2    = (ushort*)  alloc((size_t)B_CL * S2CNT * 256 * 2);
    unsigned* gmax  = (unsigned*)alloc((size_t)B_CL * 1024 * 4);
    ushort*   Wt1a  = (ushort*)  alloc((size_t)64  * 40  * 2);
    ushort*   Wt1b  = (ushort*)  alloc((size_t)64  * 72  * 2);
    ushort*   Wt1c  = (ushort*)  alloc((size_t)128 * 72  * 2);
    ushort*   Wt2a  = (ushort*)  alloc((size_t)128 * 168 * 2);
    ushort*   Wt2b  = (ushort*)  alloc((size_t)128 * 136 * 2);
    ushort*   Wt2c  = (ushort*)  alloc((size_t)256 * 136 * 2);

    const float RR1 = (float)(0.2 * 0.2);
    const float RR2 = (float)(0.4 * 0.4);

    // 1: FPS stage 1 (8 blocks x 256) + 6 weight-prep blocks
    fps1_wprep_kernel<<<B_CL + 6, 256, 0, stream>>>(pos, cpos1,
                                                    W1a, Wt1a, W1b, Wt1b, W1c, Wt1c,
                                                    W2a, Wt2a, W2b, Wt2b, W2c, Wt2c);
    // 2: radius stage 1 + FPS stage 2
    radius1_fps2_kernel<<<B_CL * S1CNT + B_CL, 256, 0, stream>>>(pos, cpos1, RR1,
                                                                 nbr1, cnt1, cpos2);
    // 3: conv1 + radius stage 2
    conv1_rad2_kernel<<<B_CL * S1CNT + B_CL * S2CNT, 256, 0, stream>>>(
        pos, cpos1, nbr1, cnt1, Wt1a, b1a, Wt1b, b1b, Wt1c, b1c, h1,
        cpos2, RR2, nbr2, cnt2);
    // 4: conv2 + gmax init
    conv2_init_kernel<<<B_CL * S2CNT + (B_CL * 1024) / 256, 256, 0, stream>>>(
        h1, cpos1, cpos2, nbr2, cnt2, Wt2a, b2a, Wt2b, b2b, Wt2c, b2c, h2, gmax);
    // 5: global MLP + max pool
    mlp3_kernel<<<(B_CL * S2CNT) / 4, 256, 0, stream>>>(h2, cpos2,
                                                        W3a, b3a, W3b, b3b, W3c, b3c, gmax);
    // 6: decode
    gmax_decode_kernel<<<(B_CL * 1024) / 256, 256, 0, stream>>>(gmax, out);
}

// Round 12
// 747.265 us; speedup vs baseline: 1.5794x; 1.2678x over previous
//
#include <hip/hip_runtime.h>
#include <hip/hip_bf16.h>
#include <cstdint>
#include <cstddef>

// Problem constants (match reference)
#define B_CL   8
#define NPTS   2048
#define S1CNT  1024
#define S2CNT  256
#define KNBR   64

typedef unsigned short ushort;
typedef __attribute__((ext_vector_type(8))) short short8b;  // 8 bf16 = MFMA A/B frag
typedef __attribute__((ext_vector_type(4))) float f32x4;    // MFMA C/D frag

__device__ __forceinline__ ushort f2bf(float f) {
    union { __hip_bfloat16 h; ushort u; } v;
    v.h = __float2bfloat16(f);
    return v.u;
}
__device__ __forceinline__ float bf2f(ushort u) {
    return __uint_as_float(((unsigned)u) << 16);
}
__device__ __forceinline__ short8b ldfrag(const ushort* p) {
    return *(const short8b*)p;
}
__device__ __forceinline__ f32x4 mfma16(short8b a, short8b b, f32x4 c) {
    return __builtin_amdgcn_mfma_f32_16x16x32_bf16(a, b, c, 0, 0, 0);
}

// Exact f32 squared distance in the reference's summation order.
__device__ __forceinline__ float dist2_exact(float ax, float ay, float az,
                                             float bx, float by, float bz) {
    float dx = __fsub_rn(ax, bx);
    float dy = __fsub_rn(ay, by);
    float dz = __fsub_rn(az, bz);
    return __fadd_rn(__fadd_rn(__fmul_rn(dx, dx), __fmul_rn(dy, dy)), __fmul_rn(dz, dz));
}

// 64-lane max-reduce of a u64 key via DPP. Result valid in lane 63.
__device__ __forceinline__ unsigned long long wave_max_u64(unsigned long long k) {
#define DPP_STEP(CTRL) {                                                            \
    unsigned lo = (unsigned)k, hi = (unsigned)(k >> 32);                            \
    unsigned nlo = (unsigned)__builtin_amdgcn_update_dpp((int)lo, (int)lo, CTRL,    \
                                                         0xf, 0xf, false);          \
    unsigned nhi = (unsigned)__builtin_amdgcn_update_dpp((int)hi, (int)hi, CTRL,    \
                                                         0xf, 0xf, false);          \
    unsigned long long nk = ((unsigned long long)nhi << 32) | nlo;                  \
    if (nk > k) k = nk;                                                             \
}
    DPP_STEP(0x111);  // row_shr:1
    DPP_STEP(0x112);  // row_shr:2
    DPP_STEP(0x114);  // row_shr:4
    DPP_STEP(0x118);  // row_shr:8
    DPP_STEP(0x142);  // row_bcast:15
    DPP_STEP(0x143);  // row_bcast:31
#undef DPP_STEP
    return k;
}

// ---------------------------------------------------------------------------
// Farthest point sampling — EXACT round-7 algorithm (measured best: 461 us
// for N=2048,S=1024), reshaped as a body fn for fused dispatches.
// One cloud per block, 256 threads. Points staged in LDS (px/py/pz); selected
// coords accumulate in LDS sel[] (dumped at the end: NO global stores in the
// loop, so the single __syncthreads never waits on vmem). Per iteration:
// update+local argmax -> u64 DPP wave max -> lane63 writes parity kbuf ->
// syncthreads -> all threads resolve 4 keys, read px[nxt] (broadcast).
// Selection is bit-exact: d2 in reference op order; key=(d2,~idx) u64-max.
// ---------------------------------------------------------------------------
template <int N, int S>
__device__ __forceinline__ void fps_body(const float* __restrict__ pos,
                                         float* __restrict__ cpos,
                                         int b, char* smem) {
    constexpr int PPT = N / 256;
    float* px  = (float*)smem;                 // [N]
    float* py  = px + N;                       // [N]
    float* pz  = py + N;                       // [N]
    float* sel = pz + N;                       // [S*3]
    unsigned long long* kbuf = (unsigned long long*)(sel + S * 3);  // [2][4]

    const int tid = threadIdx.x;
    const float* P = pos + (size_t)b * N * 3;

    float ox[PPT], oy[PPT], oz[PPT], d[PPT];
    #pragma unroll
    for (int j = 0; j < PPT; ++j) {
        int idx = tid + 256 * j;
        float x = P[idx * 3 + 0];
        float y = P[idx * 3 + 1];
        float z = P[idx * 3 + 2];
        px[idx] = x; py[idx] = y; pz[idx] = z;
        ox[j] = x; oy[j] = y; oz[j] = z;
        d[j] = 1e30f;
    }
    __syncthreads();

    float cx = px[0], cy = py[0], cz = pz[0];
    if (tid == 0) { sel[0] = cx; sel[1] = cy; sel[2] = cz; }

    for (int i = 1; i < S; ++i) {
        // update distances with current point; local argmax (strict > keeps
        // the first/min index since idx increases with j)
        float bv = -1.0f;
        int   bi = 0;
        #pragma unroll
        for (int j = 0; j < PPT; ++j) {
            int idx = tid + 256 * j;
            float dd = dist2_exact(ox[j], oy[j], oz[j], cx, cy, cz);
            float nd = fminf(d[j], dd);
            d[j] = nd;
            if (nd > bv) { bv = nd; bi = idx; }
        }
        // pack (d2, ~idx): u64 max == (max d2, then min idx). d2 >= 0 so the
        // f32 bit pattern is order-preserving.
        unsigned long long key =
            ((unsigned long long)__float_as_uint(bv) << 32) | (unsigned)(~bi);
        key = wave_max_u64(key);

        const int par = i & 1;
        if ((tid & 63) == 63) kbuf[par * 4 + (tid >> 6)] = key;
        __syncthreads();

        // every thread resolves the block winner redundantly (no 2nd barrier;
        // parity double-buffer makes next iteration's overwrite safe)
        unsigned long long kk = kbuf[par * 4 + 0];
        unsigned long long k1 = kbuf[par * 4 + 1];
        unsigned long long k2 = kbuf[par * 4 + 2];
        unsigned long long k3 = kbuf[par * 4 + 3];
        if (k1 > kk) kk = k1;
        if (k2 > kk) kk = k2;
        if (k3 > kk) kk = k3;
        int nxt = (int)(~(unsigned)kk);

        cx = px[nxt]; cy = py[nxt]; cz = pz[nxt];
        if (tid == 0) {
            sel[i * 3 + 0] = cx;
            sel[i * 3 + 1] = cy;
            sel[i * 3 + 2] = cz;
        }
    }
    __syncthreads();
    float* cp = cpos + (size_t)b * S * 3;
    for (int j = tid; j < S * 3; j += 256) cp[j] = sel[j];
}

// ---------------------------------------------------------------------------
// Radius neighbor search body (bit-exact top_k semantics), smem passed in.
// 256 threads.
// ---------------------------------------------------------------------------
template <int N>
__device__ __forceinline__ void radius_body(const float* __restrict__ pos,
                                            const float* __restrict__ cpos,
                                            int M, float rr,
                                            int* __restrict__ nbr,
                                            int* __restrict__ cnt,
                                            char* smem, int bm) {
    unsigned long long* list = (unsigned long long*)smem;
    int* c_sh = (int*)(smem + (size_t)N * 8);

    const int b   = bm / M;
    const int tid = threadIdx.x;
    const float* P = pos + (size_t)b * N * 3;

    const float cx = cpos[bm * 3 + 0];
    const float cy = cpos[bm * 3 + 1];
    const float cz = cpos[bm * 3 + 2];

    if (tid == 0) *c_sh = 0;
    __syncthreads();

    for (int i = tid; i < N; i += 256) {
        float d2 = dist2_exact(cx, cy, cz, P[i * 3], P[i * 3 + 1], P[i * 3 + 2]);
        if (d2 <= rr) {
            int slot = atomicAdd(c_sh, 1);
            list[slot] = ((unsigned long long)__float_as_uint(d2) << 32) | (unsigned int)i;
        }
    }
    __syncthreads();
    int C = *c_sh;

    if (C <= KNBR) {
        if (tid < C) nbr[(size_t)bm * KNBR + tid] = (int)(list[tid] & 0xffffffffu);
        if (tid == 0) cnt[bm] = C;
        return;
    }

    int P2 = 1;
    while (P2 < C) P2 <<= 1;
    for (int i = C + tid; i < P2; i += 256) list[i] = ~0ULL;
    __syncthreads();
    for (int k = 2; k <= P2; k <<= 1) {
        for (int j = k >> 1; j > 0; j >>= 1) {
            for (int i = tid; i < P2; i += 256) {
                int l = i ^ j;
                if (l > i) {
                    unsigned long long a = list[i], bb = list[l];
                    bool up = ((i & k) == 0);
                    if ((a > bb) == up) { list[i] = bb; list[l] = a; }
                }
            }
            __syncthreads();
        }
    }
    if (tid < KNBR) nbr[(size_t)bm * KNBR + tid] = (int)(list[tid] & 0xffffffffu);
    if (tid == 0) cnt[bm] = KNBR;
}

// ---------------------------------------------------------------------------
// Weight prep body: W [K][N] f32 -> Wt [N][Kpad] bf16, grid-stride 256 thr.
// ---------------------------------------------------------------------------
__device__ __forceinline__ void wprep_body(const float* __restrict__ W,
                                           ushort* __restrict__ Wt,
                                           int K, int N, int Kpad) {
    const int total = N * Kpad;
    for (int e = threadIdx.x; e < total; e += 256) {
        const int n = e / Kpad, k = e - n * Kpad;
        Wt[e] = (k < K) ? f2bf(W[(size_t)k * N + n]) : (ushort)0;
    }
}

// ---------------------------------------------------------------------------
// Fused dispatch 1: blocks [0,8) = FPS stage 1 (256 thr, r7 body); blocks
// [8,14) = bf16 weight transposes (fill idle CUs during the serial FPS).
// ---------------------------------------------------------------------------
__global__ __launch_bounds__(256) void fps1_wprep_kernel(
    const float* __restrict__ pos, float* __restrict__ cpos1,
    const float* __restrict__ W1a, ushort* __restrict__ Wt1a,
    const float* __restrict__ W1b, ushort* __restrict__ Wt1b,
    const float* __restrict__ W1c, ushort* __restrict__ Wt1c,
    const float* __restrict__ W2a, ushort* __restrict__ Wt2a,
    const float* __restrict__ W2b, ushort* __restrict__ Wt2b,
    const float* __restrict__ W2c, ushort* __restrict__ Wt2c) {
    // fps<2048,1024>: 3*2048*4 + 1024*3*4 + 64 = 36928 B
    __shared__ __align__(16) char smem[3 * NPTS * 4 + S1CNT * 3 * 4 + 64];
    const int bx = blockIdx.x;
    if (bx < B_CL) { fps_body<NPTS, S1CNT>(pos, cpos1, bx, smem); return; }
    switch (bx - B_CL) {
        case 0: wprep_body(W1a, Wt1a, 3,   64,  40);  break;
        case 1: wprep_body(W1b, Wt1b, 64,  64,  72);  break;
        case 2: wprep_body(W1c, Wt1c, 64,  128, 72);  break;
        case 3: wprep_body(W2a, Wt2a, 131, 128, 168); break;
        case 4: wprep_body(W2b, Wt2b, 128, 128, 136); break;
        case 5: wprep_body(W2c, Wt2c, 128, 256, 136); break;
        default: break;
    }
}

// ---------------------------------------------------------------------------
// Fused dispatch 2: blocks [0, 8192) = radius stage 1; blocks [8192, 8200) =
// FPS stage 2 (needs only cpos1; hides inside this dispatch).
// fps<1024,256> needs 3*1024*4 + 256*3*4 + 64 = 15424 B <= radius's 16400 B.
// ---------------------------------------------------------------------------
__global__ __launch_bounds__(256) void radius1_fps2_kernel(const float* __restrict__ pos,
                                                           const float* __restrict__ cpos1,
                                                           float rr1,
                                                           int* __restrict__ nbr1,
                                                           int* __restrict__ cnt1,
                                                           float* __restrict__ cpos2) {
    constexpr int    RB   = B_CL * S1CNT;                 // 8192 radius blocks
    constexpr size_t SM_R = (size_t)NPTS * 8 + 16;        // 16.4 KB
    __shared__ __align__(16) char smem[SM_R];
    if (blockIdx.x < RB)
        radius_body<NPTS>(pos, cpos1, S1CNT, rr1, nbr1, cnt1, smem, blockIdx.x);
    else
        fps_body<S1CNT, S2CNT>(cpos1, cpos2, (int)(blockIdx.x - RB), smem);
}

// ---------------------------------------------------------------------------
// SA1 PointNetConv via MFMA: [3 -> 64 -> 64 -> 128] per centroid, max-agg.
// ---------------------------------------------------------------------------
__device__ __forceinline__ void conv1_body(const float* __restrict__ pos,
                                           const float* __restrict__ cpos,
                                           const int* __restrict__ nbr,
                                           const int* __restrict__ cnt,
                                           const ushort* __restrict__ Wt1, const float* __restrict__ b1,
                                           const ushort* __restrict__ Wt2, const float* __restrict__ b2,
                                           const ushort* __restrict__ Wt3, const float* __restrict__ b3,
                                           ushort* __restrict__ h1,
                                           int bm, char* smem) {
    ushort* act1 = (ushort*)smem;            // [64*72]
    ushort* act2 = act1 + 64 * 72;           // [64*72]
    int*    snbr = (int*)(act2 + 64 * 72);   // [KNBR]

    const int b   = bm >> 10;            // S1CNT = 1024
    const int tid = threadIdx.x;
    const int C   = cnt[bm];

    const float cx = cpos[bm * 3 + 0];
    const float cy = cpos[bm * 3 + 1];
    const float cz = cpos[bm * 3 + 2];

    if (tid < KNBR) snbr[tid] = (tid < C) ? nbr[(size_t)bm * KNBR + tid] : 0;
    __syncthreads();

    const int lane = tid & 63, w = tid >> 6;
    const int lrow = lane & 15;          // frag row/col within 16
    const int lk8  = (lane >> 4) * 8;    // frag k-base
    const int rbase = (lane >> 4) * 4;   // C-frag row base
    const f32x4 zz = {0.f, 0.f, 0.f, 0.f};

    // ---- build A0 frags in registers (K=3, k>=3 zero; lanes with k-base>=8 zero)
    short8b a0[4];
    #pragma unroll
    for (int mt = 0; mt < 4; ++mt) {
        short8b a = {0, 0, 0, 0, 0, 0, 0, 0};
        if (lane < 16) {
            const int nb = snbr[mt * 16 + lrow];
            const float* pp = pos + ((size_t)b * NPTS + nb) * 3;
            a[0] = (short)f2bf(pp[0] - cx);
            a[1] = (short)f2bf(pp[1] - cy);
            a[2] = (short)f2bf(pp[2] - cz);
        }
        a0[mt] = a;
    }

    // ---- L1: K=3 (1 kstep), N=64 -> 1 ntile per wave
    {
        const int nt = w;
        short8b bf = ldfrag(Wt1 + (size_t)(nt * 16 + lrow) * 40 + lk8);
        const float bj = b1[nt * 16 + lrow];
        #pragma unroll
        for (int mt = 0; mt < 4; ++mt) {
            f32x4 acc = mfma16(a0[mt], bf, zz);
            #pragma unroll
            for (int r = 0; r < 4; ++r) {
                const int row = mt * 16 + rbase + r;
                act1[row * 72 + nt * 16 + lrow] = f2bf(fmaxf(acc[r] + bj, 0.f));
            }
        }
    }
    __syncthreads();

    // ---- L2: K=64 (2 ksteps), N=64 -> 1 ntile per wave
    {
        short8b af[4][2];
        #pragma unroll
        for (int mt = 0; mt < 4; ++mt)
            #pragma unroll
            for (int ks = 0; ks < 2; ++ks)
                af[mt][ks] = ldfrag(&act1[(mt * 16 + lrow) * 72 + ks * 32 + lk8]);
        const int nt = w;
        short8b bf0 = ldfrag(Wt2 + (size_t)(nt * 16 + lrow) * 72 + 0  + lk8);
        short8b bf1 = ldfrag(Wt2 + (size_t)(nt * 16 + lrow) * 72 + 32 + lk8);
        const float bj = b2[nt * 16 + lrow];
        #pragma unroll
        for (int mt = 0; mt < 4; ++mt) {
            f32x4 acc = mfma16(af[mt][0], bf0, zz);
            acc = mfma16(af[mt][1], bf1, acc);
            #pragma unroll
            for (int r = 0; r < 4; ++r) {
                const int row = mt * 16 + rbase + r;
                act2[row * 72 + nt * 16 + lrow] = f2bf(fmaxf(acc[r] + bj, 0.f));
            }
        }
    }
    __syncthreads();

    // ---- L3: K=64 (2 ksteps), N=128 -> 2 ntiles per wave; no relu; masked max
    {
        short8b af[4][2];
        #pragma unroll
        for (int mt = 0; mt < 4; ++mt)
            #pragma unroll
            for (int ks = 0; ks < 2; ++ks)
                af[mt][ks] = ldfrag(&act2[(mt * 16 + lrow) * 72 + ks * 32 + lk8]);
        #pragma unroll
        for (int nti = 0; nti < 2; ++nti) {
            const int nt = w * 2 + nti;
            short8b bf0 = ldfrag(Wt3 + (size_t)(nt * 16 + lrow) * 72 + 0  + lk8);
            short8b bf1 = ldfrag(Wt3 + (size_t)(nt * 16 + lrow) * 72 + 32 + lk8);
            const float bj = b3[nt * 16 + lrow];
            float vm = -3.4e38f;
            #pragma unroll
            for (int mt = 0; mt < 4; ++mt) {
                f32x4 acc = mfma16(af[mt][0], bf0, zz);
                acc = mfma16(af[mt][1], bf1, acc);
                #pragma unroll
                for (int r = 0; r < 4; ++r) {
                    const int m = mt * 16 + rbase + r;
                    if (m < C) vm = fmaxf(vm, acc[r] + bj);
                }
            }
            vm = fmaxf(vm, __shfl_xor(vm, 16));
            vm = fmaxf(vm, __shfl_xor(vm, 32));
            if (lane < 16) h1[(size_t)bm * 128 + nt * 16 + lrow] = f2bf(vm);
        }
    }
}

// Fused dispatch 3: blocks [0,8192) = conv1; blocks [8192,10240) = radius
// stage 2 (needs cpos1/cpos2 only, independent of conv1's h1).
__global__ __launch_bounds__(256) void conv1_rad2_kernel(
    const float* __restrict__ pos, const float* __restrict__ cpos1,
    const int* __restrict__ nbr1, const int* __restrict__ cnt1,
    const ushort* __restrict__ Wt1, const float* __restrict__ b1,
    const ushort* __restrict__ Wt2, const float* __restrict__ b2,
    const ushort* __restrict__ Wt3, const float* __restrict__ b3,
    ushort* __restrict__ h1,
    const float* __restrict__ cpos2, float rr2,
    int* __restrict__ nbr2, int* __restrict__ cnt2) {
    constexpr int    CB   = B_CL * S1CNT;                    // 8192 conv blocks
    constexpr size_t SM_C = (size_t)64 * 72 * 2 * 2 + KNBR * 4;
    constexpr size_t SM_R = (size_t)S1CNT * 8 + 16;
    __shared__ __align__(16) char smem[SM_C > SM_R ? SM_C : SM_R];
    if (blockIdx.x < CB)
        conv1_body(pos, cpos1, nbr1, cnt1, Wt1, b1, Wt2, b2, Wt3, b3, h1,
                   blockIdx.x, smem);
    else
        radius_body<S1CNT>(cpos1, cpos2, S2CNT, rr2, nbr2, cnt2, smem,
                           (int)(blockIdx.x - CB));
}

// ---------------------------------------------------------------------------
// SA2 PointNetConv via MFMA: [131 -> 128 -> 128 -> 256] per centroid, max-agg.
// ---------------------------------------------------------------------------
__device__ __forceinline__ void conv2_body(const ushort* __restrict__ x,     // h1 bf16
                                           const float* __restrict__ ppos,   // cpos1
                                           const float* __restrict__ cpos,   // cpos2
                                           const int* __restrict__ nbr,
                                           const int* __restrict__ cnt,
                                           const ushort* __restrict__ Wt1, const float* __restrict__ b1,
                                           const ushort* __restrict__ Wt2, const float* __restrict__ b2,
                                           const ushort* __restrict__ Wt3, const float* __restrict__ b3,
                                           ushort* __restrict__ h2, int bm) {
    __shared__ ushort act0[64 * 168];    // also reused as act2 [64][136]
    __shared__ ushort act1[64 * 136];
    __shared__ int    snbr[KNBR];
    ushort* act2 = act0;

    const int b   = bm >> 8;             // S2CNT = 256
    const int tid = threadIdx.x;
    const int C   = cnt[bm];

    const float cx = cpos[bm * 3 + 0];
    const float cy = cpos[bm * 3 + 1];
    const float cz = cpos[bm * 3 + 2];

    if (tid < KNBR) snbr[tid] = (tid < C) ? nbr[(size_t)bm * KNBR + tid] : 0;
    __syncthreads();

    for (int e = tid; e < 1024; e += 256) {          // 64 rows x 16 chunks of 8 bf16
        const int k = e >> 4, c = (e & 15) * 8;
        short8b v = {0, 0, 0, 0, 0, 0, 0, 0};
        if (k < C) v = ldfrag(x + ((size_t)b * S1CNT + snbr[k]) * 128 + c);
        *(short8b*)&act0[k * 168 + c] = v;
    }
    if (tid < KNBR) {
        const int k = tid;
        float r0 = 0.f, r1 = 0.f, r2 = 0.f;
        if (k < C) {
            const float* pp = ppos + ((size_t)b * S1CNT + snbr[k]) * 3;
            r0 = pp[0] - cx; r1 = pp[1] - cy; r2 = pp[2] - cz;
        }
        act0[k * 168 + 128] = f2bf(r0);
        act0[k * 168 + 129] = f2bf(r1);
        act0[k * 168 + 130] = f2bf(r2);
        for (int c = 131; c < 160; ++c) act0[k * 168 + c] = 0;
    }
    __syncthreads();

    const int lane = tid & 63, w = tid >> 6;
    const int lrow = lane & 15;
    const int lk8  = (lane >> 4) * 8;
    const int rbase = (lane >> 4) * 4;
    const f32x4 zz = {0.f, 0.f, 0.f, 0.f};

    // ---- L1: K=131 (5 ksteps), N=128 -> 2 ntiles per wave
    {
        short8b af[4][5];
        #pragma unroll
        for (int mt = 0; mt < 4; ++mt)
            #pragma unroll
            for (int ks = 0; ks < 5; ++ks)
                af[mt][ks] = ldfrag(&act0[(mt * 16 + lrow) * 168 + ks * 32 + lk8]);
        #pragma unroll
        for (int nti = 0; nti < 2; ++nti) {
            const int nt = w * 2 + nti;
            f32x4 acc[4] = {zz, zz, zz, zz};
            #pragma unroll
            for (int ks = 0; ks < 5; ++ks) {
                short8b bf = ldfrag(Wt1 + (size_t)(nt * 16 + lrow) * 168 + ks * 32 + lk8);
                #pragma unroll
                for (int mt = 0; mt < 4; ++mt) acc[mt] = mfma16(af[mt][ks], bf, acc[mt]);
            }
            const float bj = b1[nt * 16 + lrow];
            #pragma unroll
            for (int mt = 0; mt < 4; ++mt)
                #pragma unroll
                for (int r = 0; r < 4; ++r) {
                    const int row = mt * 16 + rbase + r;
                    act1[row * 136 + nt * 16 + lrow] = f2bf(fmaxf(acc[mt][r] + bj, 0.f));
                }
        }
    }
    __syncthreads();

    // ---- L2: K=128 (4 ksteps), N=128 -> 2 ntiles per wave (act1 -> act2)
    {
        short8b af[4][4];
        #pragma unroll
        for (int mt = 0; mt < 4; ++mt)
            #pragma unroll
            for (int ks = 0; ks < 4; ++ks)
                af[mt][ks] = ldfrag(&act1[(mt * 16 + lrow) * 136 + ks * 32 + lk8]);
        #pragma unroll
        for (int nti = 0; nti < 2; ++nti) {
            const int nt = w * 2 + nti;
            f32x4 acc[4] = {zz, zz, zz, zz};
            #pragma unroll
            for (int ks = 0; ks < 4; ++ks) {
                short8b bf = ldfrag(Wt2 + (size_t)(nt * 16 + lrow) * 136 + ks * 32 + lk8);
                #pragma unroll
                for (int mt = 0; mt < 4; ++mt) acc[mt] = mfma16(af[mt][ks], bf, acc[mt]);
            }
            const float bj = b2[nt * 16 + lrow];
            #pragma unroll
            for (int mt = 0; mt < 4; ++mt)
                #pragma unroll
                for (int r = 0; r < 4; ++r) {
                    const int row = mt * 16 + rbase + r;
                    act2[row * 136 + nt * 16 + lrow] = f2bf(fmaxf(acc[mt][r] + bj, 0.f));
                }
        }
    }
    __syncthreads();

    // ---- L3: K=128 (4 ksteps), N=256 -> 4 ntiles per wave; no relu; masked max
    {
        short8b af[4][4];
        #pragma unroll
        for (int mt = 0; mt < 4; ++mt)
            #pragma unroll
            for (int ks = 0; ks < 4; ++ks)
                af[mt][ks] = ldfrag(&act2[(mt * 16 + lrow) * 136 + ks * 32 + lk8]);
        #pragma unroll
        for (int nti = 0; nti < 4; ++nti) {
            const int nt = w * 4 + nti;
            f32x4 acc[4] = {zz, zz, zz, zz};
            #pragma unroll
            for (int ks = 0; ks < 4; ++ks) {
                short8b bf = ldfrag(Wt3 + (size_t)(nt * 16 + lrow) * 136 + ks * 32 + lk8);
                #pragma unroll
                for (int mt = 0; mt < 4; ++mt) acc[mt] = mfma16(af[mt][ks], bf, acc[mt]);
            }
            const float bj = b3[nt * 16 + lrow];
            float vm = -3.4e38f;
            #pragma unroll
            for (int mt = 0; mt < 4; ++mt)
                #pragma unroll
                for (int r = 0; r < 4; ++r) {
                    const int m = mt * 16 + rbase + r;
                    if (m < C) vm = fmaxf(vm, acc[mt][r] + bj);
                }
            vm = fmaxf(vm, __shfl_xor(vm, 16));
            vm = fmaxf(vm, __shfl_xor(vm, 32));
            if (lane < 16) h2[(size_t)bm * 256 + nt * 16 + lrow] = f2bf(vm);
        }
    }
}

// Fused dispatch 4: blocks [0,2048) = conv2; blocks [2048,2080) = gmax init.
__global__ __launch_bounds__(256) void conv2_init_kernel(
    const ushort* __restrict__ x, const float* __restrict__ ppos,
    const float* __restrict__ cpos, const int* __restrict__ nbr,
    const int* __restrict__ cnt,
    const ushort* __restrict__ Wt1, const float* __restrict__ b1,
    const ushort* __restrict__ Wt2, const float* __restrict__ b2,
    const ushort* __restrict__ Wt3, const float* __restrict__ b3,
    ushort* __restrict__ h2, unsigned* __restrict__ gmax) {
    constexpr int CB = B_CL * S2CNT;    // 2048
    if (blockIdx.x < CB)
        conv2_body(x, ppos, cpos, nbr, cnt, Wt1, b1, Wt2, b2, Wt3, b3, h2, blockIdx.x);
    else
        gmax[(size_t)(blockIdx.x - CB) * 256 + threadIdx.x] = 0u;
}

// ---------------------------------------------------------------------------
// Global MLP [259 -> 256 -> 512 -> 1024]: 4 rows per block, VALU fp32,
// atomic-max into order-preserving-encoded uint buffer. h2 input is bf16.
// ---------------------------------------------------------------------------
__device__ __forceinline__ unsigned enc_f32(float f) {
    unsigned u = __float_as_uint(f);
    return (u & 0x80000000u) ? ~u : (u | 0x80000000u);
}

__global__ __launch_bounds__(256) void mlp3_kernel(const ushort* __restrict__ h2,
                                                   const float* __restrict__ cpos2,
                                                   const float* __restrict__ W1, const float* __restrict__ b1,
                                                   const float* __restrict__ W2, const float* __restrict__ b2,
                                                   const float* __restrict__ W3, const float* __restrict__ b3,
                                                   unsigned* __restrict__ gmax) {
    __shared__ float in4[4][260];
    __shared__ float a1s[4][256];
    __shared__ float a2s[4][512];

    const int bm0 = blockIdx.x * 4;      // first of 4 consecutive s-rows (same cloud)
    const int bcl = bm0 >> 8;            // S2CNT = 256
    const int tid = threadIdx.x;

    #pragma unroll
    for (int r = 0; r < 4; ++r) {
        in4[r][tid] = bf2f(h2[(size_t)(bm0 + r) * 256 + tid]);
        if (tid < 3) in4[r][256 + tid] = cpos2[(bm0 + r) * 3 + tid];
    }
    __syncthreads();

    {   // L1: K=259, N=256
        const float bj = b1[tid];
        float acc[4] = {bj, bj, bj, bj};
        for (int i = 0; i < 259; ++i) {
            const float w = W1[i * 256 + tid];
            #pragma unroll
            for (int r = 0; r < 4; ++r) acc[r] += in4[r][i] * w;
        }
        #pragma unroll
        for (int r = 0; r < 4; ++r) a1s[r][tid] = fmaxf(acc[r], 0.f);
    }
    __syncthreads();

    {   // L2: K=256, N=512
        const float bj0 = b2[tid], bj1 = b2[tid + 256];
        float acc0[4] = {bj0, bj0, bj0, bj0};
        float acc1[4] = {bj1, bj1, bj1, bj1};
        for (int i = 0; i < 256; ++i) {
            const float w0 = W2[i * 512 + tid];
            const float w1 = W2[i * 512 + tid + 256];
            #pragma unroll
            for (int r = 0; r < 4; ++r) {
                const float a = a1s[r][i];
                acc0[r] += a * w0;
                acc1[r] += a * w1;
            }
        }
        #pragma unroll
        for (int r = 0; r < 4; ++r) {
            a2s[r][tid]       = fmaxf(acc0[r], 0.f);
            a2s[r][tid + 256] = fmaxf(acc1[r], 0.f);
        }
    }
    __syncthreads();

    {   // L3: K=512, N=1024
        float acc[4][4];
        #pragma unroll
        for (int q = 0; q < 4; ++q) {
            const float bj = b3[tid + 256 * q];
            #pragma unroll
            for (int r = 0; r < 4; ++r) acc[q][r] = bj;
        }
        for (int i = 0; i < 512; ++i) {
            float av[4];
            #pragma unroll
            for (int r = 0; r < 4; ++r) av[r] = a2s[r][i];
            #pragma unroll
            for (int q = 0; q < 4; ++q) {
                const float w = W3[i * 1024 + 256 * q + tid];
                #pragma unroll
                for (int r = 0; r < 4; ++r) acc[q][r] += av[r] * w;
            }
        }
        #pragma unroll
        for (int q = 0; q < 4; ++q)
            #pragma unroll
            for (int r = 0; r < 4; ++r)
                atomicMax(&gmax[(size_t)bcl * 1024 + 256 * q + tid], enc_f32(acc[q][r]));
    }
}

__global__ __launch_bounds__(256) void gmax_decode_kernel(const unsigned* __restrict__ gmax,
                                                          float* __restrict__ out) {
    int t = blockIdx.x * 256 + threadIdx.x;
    unsigned u = gmax[t];
    out[t] = (u & 0x80000000u) ? __uint_as_float(u ^ 0x80000000u) : __uint_as_float(~u);
}

// ---------------------------------------------------------------------------
extern "C" void kernel_launch(void* const* d_in, const int* in_sizes, int n_in,
                              void* d_out, int out_size, void* d_ws, size_t ws_size,
                              hipStream_t stream) {
    (void)in_sizes; (void)n_in; (void)out_size; (void)ws_size;

    const float* pos = (const float*)d_in[0];
    const float* W1a = (const float*)d_in[1];  const float* b1a = (const float*)d_in[2];
    const float* W1b = (const float*)d_in[3];  const float* b1b = (const float*)d_in[4];
    const float* W1c = (const float*)d_in[5];  const float* b1c = (const float*)d_in[6];
    const float* W2a = (const float*)d_in[7];  const float* b2a = (const float*)d_in[8];
    const float* W2b = (const float*)d_in[9];  const float* b2b = (const float*)d_in[10];
    const float* W2c = (const float*)d_in[11]; const float* b2c = (const float*)d_in[12];
    const float* W3a = (const float*)d_in[13]; const float* b3a = (const float*)d_in[14];
    const float* W3b = (const float*)d_in[15]; const float* b3b = (const float*)d_in[16];
    const float* W3c = (const float*)d_in[17]; const float* b3c = (const float*)d_in[18];

    float* out = (float*)d_out;

    char* ws = (char*)d_ws;
    auto alloc = [&](size_t bytes) {
        char* p = ws;
        ws += (bytes + 255) & ~(size_t)255;
        return p;
    };
    float*    cpos1 = (float*)   alloc((size_t)B_CL * S1CNT * 3 * 4);
    int*      nbr1  = (int*)     alloc((size_t)B_CL * S1CNT * KNBR * 4);
    int*      cnt1  = (int*)     alloc((size_t)B_CL * S1CNT * 4);
    ushort*   h1    = (ushort*)  alloc((size_t)B_CL * S1CNT * 128 * 2);
    float*    cpos2 = (float*)   alloc((size_t)B_CL * S2CNT * 3 * 4);
    int*      nbr2  = (int*)     alloc((size_t)B_CL * S2CNT * KNBR * 4);
    int*      cnt2  = (int*)     alloc((size_t)B_CL * S2CNT * 4);
    ushort*   h2    = (ushort*)  alloc((size_t)B_CL * S2CNT * 256 * 2);
    unsigned* gmax  = (unsigned*)alloc((size_t)B_CL * 1024 * 4);
    ushort*   Wt1a  = (ushort*)  alloc((size_t)64  * 40  * 2);
    ushort*   Wt1b  = (ushort*)  alloc((size_t)64  * 72  * 2);
    ushort*   Wt1c  = (ushort*)  alloc((size_t)128 * 72  * 2);
    ushort*   Wt2a  = (ushort*)  alloc((size_t)128 * 168 * 2);
    ushort*   Wt2b  = (ushort*)  alloc((size_t)128 * 136 * 2);
    ushort*   Wt2c  = (ushort*)  alloc((size_t)256 * 136 * 2);

    const float RR1 = (float)(0.2 * 0.2);
    const float RR2 = (float)(0.4 * 0.4);

    // 1: FPS stage 1 (8 blocks x 256, r7 body) + 6 weight-prep blocks
    fps1_wprep_kernel<<<B_CL + 6, 256, 0, stream>>>(pos, cpos1,
                                                    W1a, Wt1a, W1b, Wt1b, W1c, Wt1c,
                                                    W2a, Wt2a, W2b, Wt2b, W2c, Wt2c);
    // 2: radius stage 1 + FPS stage 2
    radius1_fps2_kernel<<<B_CL * S1CNT + B_CL, 256, 0, stream>>>(pos, cpos1, RR1,
                                                                 nbr1, cnt1, cpos2);
    // 3: conv1 + radius stage 2
    conv1_rad2_kernel<<<B_CL * S1CNT + B_CL * S2CNT, 256, 0, stream>>>(
        pos, cpos1, nbr1, cnt1, Wt1a, b1a, Wt1b, b1b, Wt1c, b1c, h1,
        cpos2, RR2, nbr2, cnt2);
    // 4: conv2 + gmax init
    conv2_init_kernel<<<B_CL * S2CNT + (B_CL * 1024) / 256, 256, 0, stream>>>(
        h1, cpos1, cpos2, nbr2, cnt2, Wt2a, b2a, Wt2b, b2b, Wt2c, b2c, h2, gmax);
    // 5: global MLP + max pool
    mlp3_kernel<<<(B_CL * S2CNT) / 4, 256, 0, stream>>>(h2, cpos2,
                                                        W3a, b3a, W3b, b3b, W3c, b3c, gmax);
    // 6: decode
    gmax_decode_kernel<<<(B_CL * 1024) / 256, 256, 0, stream>>>(gmax, out);
}